// Round 11
// baseline (253.871 us; speedup 1.0000x reference)
//
#include <hip/hip_runtime.h>
#include <cstdint>
#include <cstddef>

#define B 16
#define S 1024
#define D 768
#define H 12
#define HD 64
#define NTOK (B * S)        // 16384
#define QKV_N (3 * D)       // 2304
#define SCALE 0.125f        // 64^-0.5
#define C2 2.88539008f      // 2.0 * log2(e): fixed softmax shift (nat-log C=2)
#define GK 768              // GEMM contraction dim (both GEMMs)
#define NT_K 12             // GK / 64

typedef _Float16 f16x8 __attribute__((ext_vector_type(8)));
typedef _Float16 f16x4 __attribute__((ext_vector_type(4)));
typedef float f32x4 __attribute__((ext_vector_type(4)));

typedef __attribute__((address_space(3))) void as3_void;
typedef const __attribute__((address_space(1))) void as1_void;

#if defined(__has_builtin)
#if __has_builtin(__builtin_amdgcn_exp2f)
#define EXP2(x) __builtin_amdgcn_exp2f(x)
#else
#define EXP2(x) exp2f(x)
#endif
#else
#define EXP2(x) exp2f(x)
#endif

// ---------------- mask normalization (bool-byte vs int32 agnostic) -------------
__global__ __launch_bounds__(256) void normalize_mask_kernel(
    const unsigned char* __restrict__ raw, int* __restrict__ outm, int n) {
    __shared__ int s_isbyte;
    const int tid = threadIdx.x;
    if (tid == 0) s_isbyte = 0;
    __syncthreads();
    int found = 0;
    for (int i = tid; i < n; i += 256) {
        if ((i & 3) != 0 && raw[i] != 0) found = 1;
    }
    if (found) atomicOr(&s_isbyte, 1);
    __syncthreads();
    const int isbyte = s_isbyte;
    if (isbyte) {
        for (int i = tid; i < n; i += 256) outm[i] = raw[i] ? 1 : 0;
    } else {
        const int* r32 = (const int*)raw;
        for (int i = tid; i < n; i += 256) outm[i] = r32[i] ? 1 : 0;
    }
}

// ---------------- f32 -> f16 conversion (3 tensors, one launch) ----------------
__global__ __launch_bounds__(256) void cvt_all_f16(
    const float* __restrict__ in0, _Float16* __restrict__ out0, int n0,
    const float* __restrict__ in1, _Float16* __restrict__ out1, int n1,
    const float* __restrict__ in2, _Float16* __restrict__ out2, int n2) {
    int i = blockIdx.x * 256 + threadIdx.x;
    const float* in;
    _Float16* out;
    if (i < n0) { in = in0; out = out0; }
    else if (i < n0 + n1) { i -= n0; in = in1; out = out1; }
    else { i -= n0 + n1; in = in2; out = out2; if (i >= n2) return; }
    const float4 v = ((const float4*)in)[i];
    f16x4 o;
    o[0] = (_Float16)v.x; o[1] = (_Float16)v.y;
    o[2] = (_Float16)v.z; o[3] = (_Float16)v.w;
    ((f16x4*)out)[i] = o;
}

// ---------------- f16 MFMA GEMM: C[m,n] = sum_k A[m,k]*W[n,k] + bias[n] --------
// 128x128 tile, BK=64, 256 threads = 4 waves (2x2 of 64x64).
// Double-buffered LDS + counted vmcnt(8) across raw s_barrier.
// XOR swizzle (slot ^= row&7) on global source AND ds_read addr (conflict-free).
// F16OUT=1: row-major f16 out (no rowmask).  F16OUT=0: f32 out + rowmask zero.
template <int F16OUT>
__global__ __launch_bounds__(256, 2) void gemm16(
    const _Float16* __restrict__ A, const _Float16* __restrict__ Wm,
    const float* __restrict__ bias, const int* __restrict__ rowmask,
    int N, float* __restrict__ outf, _Float16* __restrict__ outh) {
    __shared__ _Float16 As[2][128 * 64];   // 2 x 16 KB
    __shared__ _Float16 Bs[2][128 * 64];   // 2 x 16 KB

    const int tid = threadIdx.x;
    const int w = tid >> 6, l = tid & 63;
    const int wm = (w >> 1) * 64, wn = (w & 1) * 64;
    const int lg = l >> 4, lc = l & 15;

    // XCD-aware decode: bid%8 = XCD; per XCD a 16-row M-stripe, N-major inside.
    const int bid = blockIdx.x;
    const int xcd = bid & 7;
    const int idx = bid >> 3;
    const int bn = (idx >> 4) * 128;
    const int bm = (xcd * 16 + (idx & 15)) * 128;

    f32x4 acc[4][4] = {};

#define STAGE(T, BUF)                                                           \
    {                                                                           \
        const int kt_ = (T) * 64;                                               \
        _Pragma("unroll")                                                       \
        for (int i_ = 0; i_ < 4; ++i_) {                                        \
            const int ci_ = (w << 2) + i_;       /* 0..15 */                    \
            const int r_ = (ci_ << 3) + (l >> 3);                               \
            const int c16_ = (l & 7) ^ (r_ & 7);                                \
            __builtin_amdgcn_global_load_lds(                                   \
                (as1_void*)(A + (size_t)(bm + r_) * GK + kt_ + c16_ * 8),       \
                (as3_void*)(&As[BUF][ci_ * 512]), 16, 0, 0);                    \
            __builtin_amdgcn_global_load_lds(                                   \
                (as1_void*)(Wm + (size_t)(bn + r_) * GK + kt_ + c16_ * 8),      \
                (as3_void*)(&Bs[BUF][ci_ * 512]), 16, 0, 0);                    \
        }                                                                       \
    }

    STAGE(0, 0)

    for (int t = 0; t < NT_K; ++t) {
        const int cur = t & 1;
        if (t + 1 < NT_K) {
            STAGE(t + 1, cur ^ 1)
            asm volatile("s_waitcnt vmcnt(8)" ::: "memory");
        } else {
            asm volatile("s_waitcnt vmcnt(0)" ::: "memory");
        }
        __builtin_amdgcn_s_barrier();   // buf[cur] populated & visible

        const _Float16* sA = &As[cur][0];
        const _Float16* sB = &Bs[cur][0];
        __builtin_amdgcn_s_setprio(1);
#pragma unroll
        for (int kk = 0; kk < 2; ++kk) {
            const int c16 = ((kk << 2) + lg) ^ (lc & 7);
            f16x8 af[4], bf[4];
#pragma unroll
            for (int ni = 0; ni < 4; ++ni)
                bf[ni] = *(const f16x8*)&sB[(wn + ni * 16 + lc) * 64 + c16 * 8];
#pragma unroll
            for (int mi = 0; mi < 4; ++mi)
                af[mi] = *(const f16x8*)&sA[(wm + mi * 16 + lc) * 64 + c16 * 8];
#pragma unroll
            for (int mi = 0; mi < 4; ++mi)
#pragma unroll
                for (int ni = 0; ni < 4; ++ni)
                    acc[mi][ni] = __builtin_amdgcn_mfma_f32_16x16x32_f16(
                        af[mi], bf[ni], acc[mi][ni], 0, 0, 0);
        }
        __builtin_amdgcn_s_setprio(0);
        __builtin_amdgcn_s_barrier();   // all waves done reading buf[cur]
    }
#undef STAGE

    float bs[4];
#pragma unroll
    for (int ni = 0; ni < 4; ++ni) bs[ni] = bias[bn + wn + ni * 16 + lc];

    if (F16OUT) {
#pragma unroll
        for (int mi = 0; mi < 4; ++mi) {
#pragma unroll
            for (int j = 0; j < 4; ++j) {
                const int m = bm + wm + mi * 16 + lg * 4 + j;
#pragma unroll
                for (int ni = 0; ni < 4; ++ni) {
                    const int col = bn + wn + ni * 16 + lc;
                    outh[(size_t)m * N + col] = (_Float16)(acc[mi][ni][j] + bs[ni]);
                }
            }
        }
    } else {
#pragma unroll
        for (int mi = 0; mi < 4; ++mi) {
#pragma unroll
            for (int j = 0; j < 4; ++j) {
                const int m = bm + wm + mi * 16 + lg * 4 + j;
                const int mv = rowmask[m];
#pragma unroll
                for (int ni = 0; ni < 4; ++ni) {
                    const int col = bn + wn + ni * 16 + lc;
                    outf[(size_t)m * N + col] = mv ? acc[mi][ni][j] + bs[ni] : 0.f;
                }
            }
        }
    }
}

// ---------------- V transpose: qkv row-major -> vt[B,H,64,S] -------------------
__global__ __launch_bounds__(256) void vtrans_kernel(
    const _Float16* __restrict__ qkv, _Float16* __restrict__ vt) {
    __shared__ _Float16 vs[64][66];
    const int blk = blockIdx.x;
    const int s64 = blk & 15;
    const int h = (blk >> 4) % H;
    const int b = blk / (16 * H);
    const int tid = threadIdx.x;

    const _Float16* src =
        qkv + ((size_t)(b * S + s64 * 64)) * QKV_N + 2 * D + h * HD;
#pragma unroll
    for (int i = 0; i < 2; ++i) {
        const int k = i * 32 + (tid >> 3);
        *(f16x8*)&vs[k][(tid & 7) * 8] =
            *(const f16x8*)(src + (size_t)k * QKV_N + (tid & 7) * 8);
    }
    __syncthreads();

    const int hd = tid >> 2;
    const size_t obase = ((size_t)(b * H + h) * HD + hd) * S + s64 * 64;
#pragma unroll
    for (int j = 0; j < 2; ++j) {
        const int k0 = (j * 4 + (tid & 3)) * 8;
        f16x8 o;
#pragma unroll
        for (int e = 0; e < 8; ++e) o[e] = vs[k0 + e][hd];
        *(f16x8*)(vt + obase + k0) = o;
    }
}

// ---------------- flash attention: swapped QK^T, register-resident P ----------
// grid: B*H*(S/64), XCD-grouped. Double-buffered K/V LDS, one barrier/tile.
// K staged via global_load_lds into linear [64][64] with XOR swizzle
// (inverse-swizzled global source + swizzled ds_read — r4-proven pattern).
// V in [hd][key] LDS with row stride 68 halves (34 dwords == 2 mod 32):
// b64 PV-read phases cover all 32 banks -> zero conflicts, no rotation.
// Mask bias enters as the MFMA C-operand init (no VALU adds).
__global__ __launch_bounds__(256) void attn_kernel(
    const _Float16* __restrict__ qkv, const _Float16* __restrict__ vtb,
    const int* __restrict__ mask, _Float16* __restrict__ ctx) {
    __shared__ _Float16 ksm[2][64 * 64];   // 16 KB: [buf][row*64 + swz-col]
    __shared__ _Float16 vsm[2][64 * 68];   // 17.4 KB: [buf][hd*68 + key]
    __shared__ float mbias[S];             // 4 KB: per-key softmax bias

    const int blk = blockIdx.x;
    // XCD grouping: 3072 blocks = 8 xcd * 24 bh * 16 qt
    const int xcd = blk & 7;
    const int idx = blk >> 3;
    const int bh_ = xcd * 24 + (idx >> 4);
    const int qt = idx & 15;
    const int h = bh_ % H;
    const int b = bh_ / H;
    const int tid = threadIdx.x;
    const int w = tid >> 6, lane = tid & 63;
    const int lg = lane >> 4, lc = lane & 15;

    const size_t bh = (size_t)(b * H + h);
    const _Float16* Kp = qkv + (size_t)(b * S) * QKV_N + D + h * HD; // +row*2304
    const _Float16* Vt = vtb + bh * HD * S;
    const int* mrow = mask + b * S;

    // K staging geometry: instr i covers 16B-chunks c = i*256 + w*64 + lane.
    // chunk c -> (row r = c>>3, slot s = c&7); source col16 = s ^ (r&7).
    const int r0 = w * 8 + (lane >> 3);
    const int s0 = lane & 7;
    const int koff0 = r0 * QKV_N + (s0 ^ (r0 & 7)) * 8;           // halves
    const int koff1 = (32 + r0) * QKV_N + (s0 ^ ((32 + r0) & 7)) * 8;
    // V staging (reg-staged)
    const int srow = tid >> 3;          // 0..31
    const int scol = (tid & 7) * 8;     // 0,8,..,56

#define KSTAGE(KT, BUF)                                                        \
    {                                                                          \
        __builtin_amdgcn_global_load_lds(                                      \
            (as1_void*)(Kp + (size_t)(KT) * QKV_N + koff0),                    \
            (as3_void*)(&ksm[BUF][w * 512]), 16, 0, 0);                        \
        __builtin_amdgcn_global_load_lds(                                      \
            (as1_void*)(Kp + (size_t)(KT) * QKV_N + koff1),                    \
            (as3_void*)(&ksm[BUF][2048 + w * 512]), 16, 0, 0);                 \
    }

    // Q fragment: lane holds Q[q = qt*64+w*16+lc][hd = lg*8+e (+32)], prescaled
    const int qrow_frag = qt * 64 + w * 16 + lc;
    const _Float16* Qp = qkv + (size_t)(b * S + qrow_frag) * QKV_N + h * HD;
    f16x8 qf0 = *(const f16x8*)(Qp + lg * 8);
    f16x8 qf1 = *(const f16x8*)(Qp + 32 + lg * 8);
    const _Float16 qs = (_Float16)(0.125f * 1.44269504f);
    qf0 *= qs; qf1 *= qs;

    // mask-bias table (all 1024 keys, once): valid ? -C2 : -1e9
#pragma unroll
    for (int i = 0; i < 4; ++i)
        mbias[i * 256 + tid] = mrow[i * 256 + tid] ? -C2 : -1e9f;

    // prologue: stage tile 0
    KSTAGE(0, 0)
    {
        const f16x8 gv0 = *(const f16x8*)(Vt + (size_t)srow * S + scol);
        const f16x8 gv1 = *(const f16x8*)(Vt + (size_t)(32 + srow) * S + scol);
        asm volatile("s_waitcnt vmcnt(0)" ::: "memory");
        *(f16x4*)&vsm[0][srow * 68 + scol] = ((const f16x4*)&gv0)[0];
        *(f16x4*)&vsm[0][srow * 68 + scol + 4] = ((const f16x4*)&gv0)[1];
        *(f16x4*)&vsm[0][(32 + srow) * 68 + scol] = ((const f16x4*)&gv1)[0];
        *(f16x4*)&vsm[0][(32 + srow) * 68 + scol + 4] = ((const f16x4*)&gv1)[1];
    }
    __syncthreads();

    f32x4 acc[4] = {};
    float l_loc = 0.f;

    for (int it = 0; it < S / 64; ++it) {
        const int cur = it & 1;
        const int ktn = (it + 1) * 64;
        const bool pref = (it + 1 < S / 64);
        f16x8 gv0, gv1;
        if (pref) {  // issue next tile's loads early (hide under compute)
            KSTAGE(ktn, cur ^ 1)
            gv0 = *(const f16x8*)(Vt + (size_t)srow * S + ktn + scol);
            gv1 = *(const f16x8*)(Vt + (size_t)(32 + srow) * S + ktn + scol);
        }

#pragma unroll
        for (int t = 0; t < 4; ++t) {
            // swapped QK^T: S[key = t*16+4lg+j][q = lc]; C-init = mask bias
            const int krow = (t * 16 + lc) * 64;
            const f16x8 kfa =
                *(const f16x8*)&ksm[cur][krow + (lg ^ (lc & 7)) * 8];
            const f16x8 kfb =
                *(const f16x8*)&ksm[cur][krow + ((4 + lg) ^ (lc & 7)) * 8];
            f32x4 c = *(const f32x4*)&mbias[it * 64 + t * 16 + 4 * lg];
            c = __builtin_amdgcn_mfma_f32_16x16x32_f16(kfa, qf0, c, 0, 0, 0);
            c = __builtin_amdgcn_mfma_f32_16x16x32_f16(kfb, qf1, c, 0, 0, 0);

            const float p0 = EXP2(c[0]);
            const float p1 = EXP2(c[1]);
            const float p2 = EXP2(c[2]);
            const float p3 = EXP2(c[3]);
            l_loc += (p0 + p1) + (p2 + p3);

            // pack to f16 A-fragment (register-resident P, no LDS)
            const auto u0 = __builtin_amdgcn_cvt_pkrtz(p0, p1);  // __fp16 x2
            const auto u1 = __builtin_amdgcn_cvt_pkrtz(p2, p3);
            f16x4 pp;
            pp[0] = (_Float16)u0[0]; pp[1] = (_Float16)u0[1];
            pp[2] = (_Float16)u1[0]; pp[3] = (_Float16)u1[1];

            // PV over this 16-key tile: 4 hd-groups of 16
#pragma unroll
            for (int g = 0; g < 4; ++g) {
                const f16x4 vf =
                    *(const f16x4*)&vsm[cur][(g * 16 + lc) * 68 + t * 16 + lg * 4];
                acc[g] = __builtin_amdgcn_mfma_f32_16x16x16f16(pp, vf, acc[g], 0, 0, 0);
            }
        }

        if (pref) {  // K already landing in ksm[cur^1]; write V after drain
            asm volatile("s_waitcnt vmcnt(0)" ::: "memory");
            *(f16x4*)&vsm[cur ^ 1][srow * 68 + scol] = ((const f16x4*)&gv0)[0];
            *(f16x4*)&vsm[cur ^ 1][srow * 68 + scol + 4] = ((const f16x4*)&gv0)[1];
            *(f16x4*)&vsm[cur ^ 1][(32 + srow) * 68 + scol] = ((const f16x4*)&gv1)[0];
            *(f16x4*)&vsm[cur ^ 1][(32 + srow) * 68 + scol + 4] = ((const f16x4*)&gv1)[1];
        }
        __syncthreads();   // writes visible; all reads of buf[cur] done
    }
#undef KSTAGE

    // epilogue: l_loc holds partial row-sum for q=lc over keys 4lg+j;
    // reduce across the 4 lg-groups, then redistribute to C-row owners.
    float l = l_loc;
    l += __shfl_xor(l, 16);
    l += __shfl_xor(l, 32);
    const float inv_lc = l > 0.f ? 1.f / l : 0.f;

#pragma unroll
    for (int j = 0; j < 4; ++j) {
        const int qin = 4 * lg + j;
        const float invj = __shfl(inv_lc, qin);   // lane qin (lg=0) has q=qin
        const int qr = qt * 64 + w * 16 + qin;
        const float invq = mrow[qr] ? invj : 0.f;
        const size_t o = ((size_t)(b * S + qr)) * D + h * HD;
#pragma unroll
        for (int g = 0; g < 4; ++g)
            ctx[o + 16 * g + lc] = (_Float16)(acc[g][j] * invq);
    }
}

// -------------------------------------------------------------------------------
extern "C" void kernel_launch(void* const* d_in, const int* in_sizes, int n_in,
                              void* d_out, int out_size, void* d_ws, size_t ws_size,
                              hipStream_t stream) {
    const float* hidden = (const float*)d_in[0];
    const unsigned char* maskraw = (const unsigned char*)d_in[1];
    const float* qkv_w = (const float*)d_in[2];
    const float* qkv_b = (const float*)d_in[3];
    const float* proj_w = (const float*)d_in[4];
    const float* proj_b = (const float*)d_in[5];
    float* out = (float*)d_out;

    char* ws = (char*)d_ws;
    size_t off = 0;
    int* maskN = (int*)(ws + off);            off += (size_t)NTOK * 4;
    _Float16* hid16 = (_Float16*)(ws + off);  off += (size_t)NTOK * D * 2;
    _Float16* qkvw16 = (_Float16*)(ws + off); off += (size_t)QKV_N * D * 2;
    _Float16* projw16 = (_Float16*)(ws + off); off += (size_t)D * D * 2;
    _Float16* qkv16 = (_Float16*)(ws + off);  off += (size_t)NTOK * QKV_N * 2;
    _Float16* vt = (_Float16*)(ws + off);     off += (size_t)NTOK * D * 2;
    _Float16* ctx16 = (_Float16*)(ws + off);  off += (size_t)NTOK * D * 2;

    normalize_mask_kernel<<<1, 256, 0, stream>>>(maskraw, maskN, NTOK);

    const int n0 = NTOK * D / 4, n1 = QKV_N * D / 4, n2 = D * D / 4;
    cvt_all_f16<<<(n0 + n1 + n2 + 255) / 256, 256, 0, stream>>>(
        hidden, hid16, n0, qkv_w, qkvw16, n1, proj_w, projw16, n2);

    // qkv GEMM: blocks = (M/128)*(N/128) = 128*18 = 2304 (2304%8==0)
    gemm16<1><<<dim3(2304), 256, 0, stream>>>(
        hid16, qkvw16, qkv_b, nullptr, QKV_N, nullptr, qkv16);

    vtrans_kernel<<<dim3(B * H * (S / 64)), 256, 0, stream>>>(qkv16, vt);

    attn_kernel<<<dim3(B * H * (S / 64)), 256, 0, stream>>>(qkv16, vt, maskN, ctx16);

    // proj GEMM: blocks = 128*6 = 768 (768%8==0)
    gemm16<0><<<dim3(768), 256, 0, stream>>>(
        ctx16, projw16, proj_b, maskN, D, out, nullptr);
}

// Round 12
// 207.655 us; speedup vs baseline: 1.2226x; 1.2226x over previous
//
#include <hip/hip_runtime.h>
#include <cstdint>
#include <cstddef>

#define B 16
#define S 1024
#define D 768
#define H 12
#define HD 64
#define NTOK (B * S)        // 16384
#define QKV_N (3 * D)       // 2304
#define SCALE 0.125f        // 64^-0.5
#define C2 2.88539008f      // 2.0 * log2(e): fixed softmax shift (nat-log C=2)
#define GK 768              // GEMM contraction dim (both GEMMs)
#define NT_K 12             // GK / 64

typedef _Float16 f16x8 __attribute__((ext_vector_type(8)));
typedef _Float16 f16x4 __attribute__((ext_vector_type(4)));
typedef __fp16 fp16x2 __attribute__((ext_vector_type(2)));
typedef float f32x4 __attribute__((ext_vector_type(4)));

typedef __attribute__((address_space(3))) void as3_void;
typedef const __attribute__((address_space(1))) void as1_void;

#if defined(__has_builtin)
#if __has_builtin(__builtin_amdgcn_exp2f)
#define EXP2(x) __builtin_amdgcn_exp2f(x)
#else
#define EXP2(x) exp2f(x)
#endif
#else
#define EXP2(x) exp2f(x)
#endif

// ---------------- mask normalization (bool-byte vs int32 agnostic) -------------
__global__ __launch_bounds__(256) void normalize_mask_kernel(
    const unsigned char* __restrict__ raw, int* __restrict__ outm, int n) {
    __shared__ int s_isbyte;
    const int tid = threadIdx.x;
    if (tid == 0) s_isbyte = 0;
    __syncthreads();
    int found = 0;
    for (int i = tid; i < n; i += 256) {
        if ((i & 3) != 0 && raw[i] != 0) found = 1;
    }
    if (found) atomicOr(&s_isbyte, 1);
    __syncthreads();
    const int isbyte = s_isbyte;
    if (isbyte) {
        for (int i = tid; i < n; i += 256) outm[i] = raw[i] ? 1 : 0;
    } else {
        const int* r32 = (const int*)raw;
        for (int i = tid; i < n; i += 256) outm[i] = r32[i] ? 1 : 0;
    }
}

// ---------------- f32 -> f16 conversion (3 tensors, one launch) ----------------
__global__ __launch_bounds__(256) void cvt_all_f16(
    const float* __restrict__ in0, _Float16* __restrict__ out0, int n0,
    const float* __restrict__ in1, _Float16* __restrict__ out1, int n1,
    const float* __restrict__ in2, _Float16* __restrict__ out2, int n2) {
    int i = blockIdx.x * 256 + threadIdx.x;
    const float* in;
    _Float16* out;
    if (i < n0) { in = in0; out = out0; }
    else if (i < n0 + n1) { i -= n0; in = in1; out = out1; }
    else { i -= n0 + n1; in = in2; out = out2; if (i >= n2) return; }
    const float4 v = ((const float4*)in)[i];
    f16x4 o;
    o[0] = (_Float16)v.x; o[1] = (_Float16)v.y;
    o[2] = (_Float16)v.z; o[3] = (_Float16)v.w;
    ((f16x4*)out)[i] = o;
}

// ---------------- f16 MFMA GEMM: C[m,n] = sum_k A[m,k]*W[n,k] + bias[n] --------
// 128x128 tile, BK=64, 256 threads = 4 waves (2x2 of 64x64).
// Double-buffered LDS + counted vmcnt(8) across raw s_barrier.
// XOR swizzle (slot ^= row&7) on global source AND ds_read addr (conflict-free).
// MODE 1 (QKV): Q,K column-blocks (bn<1536) -> row-major f16 qkv16;
//               V column-blocks (bn>=1536, never straddle) -> transposed into
//               vt[B,H,64,S] via post-loop LDS transpose (smem reuse).
// MODE 0 (proj): f32 out + rowmask zeroing.
template <int MODE>
__global__ __launch_bounds__(256, 2) void gemm16(
    const _Float16* __restrict__ A, const _Float16* __restrict__ Wm,
    const float* __restrict__ bias, const int* __restrict__ rowmask,
    int N, float* __restrict__ outf, _Float16* __restrict__ outh,
    _Float16* __restrict__ vtb) {
    __shared__ _Float16 smem[32768];   // 64 KB: As[2]=smem+buf*8192, Bs[2]=+16384

    const int tid = threadIdx.x;
    const int w = tid >> 6, l = tid & 63;
    const int wm = (w >> 1) * 64, wn = (w & 1) * 64;
    const int lg = l >> 4, lc = l & 15;

    // XCD-aware decode: bid%8 = XCD; per XCD a 16-row M-stripe, N-major inside.
    const int bid = blockIdx.x;
    const int xcd = bid & 7;
    const int idx = bid >> 3;
    const int bn = (idx >> 4) * 128;
    const int bm = (xcd * 16 + (idx & 15)) * 128;

    f32x4 acc[4][4] = {};

#define STAGE(T, BUF)                                                           \
    {                                                                           \
        const int kt_ = (T) * 64;                                               \
        _Pragma("unroll")                                                       \
        for (int i_ = 0; i_ < 4; ++i_) {                                        \
            const int ci_ = (w << 2) + i_;       /* 0..15 */                    \
            const int r_ = (ci_ << 3) + (l >> 3);                               \
            const int c16_ = (l & 7) ^ (r_ & 7);                                \
            __builtin_amdgcn_global_load_lds(                                   \
                (as1_void*)(A + (size_t)(bm + r_) * GK + kt_ + c16_ * 8),       \
                (as3_void*)(smem + (BUF) * 8192 + ci_ * 512), 16, 0, 0);        \
            __builtin_amdgcn_global_load_lds(                                   \
                (as1_void*)(Wm + (size_t)(bn + r_) * GK + kt_ + c16_ * 8),      \
                (as3_void*)(smem + 16384 + (BUF) * 8192 + ci_ * 512), 16, 0, 0);\
        }                                                                       \
    }

    STAGE(0, 0)

    for (int t = 0; t < NT_K; ++t) {
        const int cur = t & 1;
        if (t + 1 < NT_K) {
            STAGE(t + 1, cur ^ 1)
            asm volatile("s_waitcnt vmcnt(8)" ::: "memory");
        } else {
            asm volatile("s_waitcnt vmcnt(0)" ::: "memory");
        }
        __builtin_amdgcn_s_barrier();   // buf[cur] populated & visible

        const _Float16* sA = smem + cur * 8192;
        const _Float16* sB = smem + 16384 + cur * 8192;
        __builtin_amdgcn_s_setprio(1);
#pragma unroll
        for (int kk = 0; kk < 2; ++kk) {
            const int c16 = ((kk << 2) + lg) ^ (lc & 7);
            f16x8 af[4], bf[4];
#pragma unroll
            for (int ni = 0; ni < 4; ++ni)
                bf[ni] = *(const f16x8*)&sB[(wn + ni * 16 + lc) * 64 + c16 * 8];
#pragma unroll
            for (int mi = 0; mi < 4; ++mi)
                af[mi] = *(const f16x8*)&sA[(wm + mi * 16 + lc) * 64 + c16 * 8];
#pragma unroll
            for (int mi = 0; mi < 4; ++mi)
#pragma unroll
                for (int ni = 0; ni < 4; ++ni)
                    acc[mi][ni] = __builtin_amdgcn_mfma_f32_16x16x32_f16(
                        af[mi], bf[ni], acc[mi][ni], 0, 0, 0);
        }
        __builtin_amdgcn_s_setprio(0);
        __builtin_amdgcn_s_barrier();   // all waves done reading buf[cur]
    }
#undef STAGE

    float bs[4];
#pragma unroll
    for (int ni = 0; ni < 4; ++ni) bs[ni] = bias[bn + wn + ni * 16 + lc];

    if (MODE == 1) {
        if (bn < 1536) {
            // Q,K: row-major f16
#pragma unroll
            for (int mi = 0; mi < 4; ++mi) {
#pragma unroll
                for (int j = 0; j < 4; ++j) {
                    const int m = bm + wm + mi * 16 + lg * 4 + j;
#pragma unroll
                    for (int ni = 0; ni < 4; ++ni) {
                        const int col = bn + wn + ni * 16 + lc;
                        outh[(size_t)m * N + col] =
                            (_Float16)(acc[mi][ni][j] + bs[ni]);
                    }
                }
            }
        } else {
            // V: transpose via LDS (smem reuse; [128 col][136] stride)
#pragma unroll
            for (int mi = 0; mi < 4; ++mi) {
#pragma unroll
                for (int ni = 0; ni < 4; ++ni) {
                    f16x4 v4;
#pragma unroll
                    for (int j = 0; j < 4; ++j)
                        v4[j] = (_Float16)(acc[mi][ni][j] + bs[ni]);
                    const int nl = wn + ni * 16 + lc;
                    const int ml = wm + mi * 16 + lg * 4;
                    *(f16x4*)&smem[nl * 136 + ml] = v4;
                }
            }
            __syncthreads();
            const int r = tid >> 1;            // local col 0..127 (hd dim)
            const int c0 = (tid & 1) * 64;     // token sub-block
            const int col0 = bn - 1536 + r;    // 0..767
            const int hh = col0 >> 6, hd = col0 & 63;
            const int bb = bm >> 10;
            const int s0 = (bm & 1023) + c0;
            _Float16* dst = vtb + ((size_t)(bb * H + hh) * HD + hd) * S + s0;
#pragma unroll
            for (int e = 0; e < 8; ++e)
                *(f16x8*)(dst + e * 8) = *(const f16x8*)&smem[r * 136 + c0 + e * 8];
        }
    } else {
#pragma unroll
        for (int mi = 0; mi < 4; ++mi) {
#pragma unroll
            for (int j = 0; j < 4; ++j) {
                const int m = bm + wm + mi * 16 + lg * 4 + j;
                const int mv = rowmask[m];
#pragma unroll
                for (int ni = 0; ni < 4; ++ni) {
                    const int col = bn + wn + ni * 16 + lc;
                    outf[(size_t)m * N + col] = mv ? acc[mi][ni][j] + bs[ni] : 0.f;
                }
            }
        }
    }
}

// ---------------- flash attention: swapped QK^T, register-resident P ----------
// grid: B*H*(S/128) = 1536, XCD-grouped. QBLK=128: each wave owns TWO 16-row
// q-groups (+0, +64) — K-frag reads, staging, barriers amortized 2x.
// K staged via global_load_lds (XOR swizzle both sides); V LDS stride 68
// (conflict-free b64 reads); mask bias as MFMA C-init; fdot2 row-sums.
__global__ __launch_bounds__(256) void attn_kernel(
    const _Float16* __restrict__ qkv, const _Float16* __restrict__ vtb,
    const int* __restrict__ mask, _Float16* __restrict__ ctx) {
    __shared__ _Float16 ksm[2][64 * 64];   // 16 KB: [buf][row*64 + swz-col]
    __shared__ _Float16 vsm[2][64 * 68];   // 17.4 KB: [buf][hd*68 + key]
    __shared__ float mbias[S];             // 4 KB

    const int blk = blockIdx.x;
    // XCD grouping: 1536 blocks = 8 xcd * 24 bh * 8 qt
    const int xcd = blk & 7;
    const int idx = blk >> 3;
    const int bh_ = xcd * 24 + (idx >> 3);
    const int qt = idx & 7;
    const int h = bh_ % H;
    const int b = bh_ / H;
    const int tid = threadIdx.x;
    const int w = tid >> 6, lane = tid & 63;
    const int lg = lane >> 4, lc = lane & 15;

    const size_t bh = (size_t)(b * H + h);
    const _Float16* Kp = qkv + (size_t)(b * S) * QKV_N + D + h * HD; // +row*2304
    const _Float16* Vt = vtb + bh * HD * S;
    const int* mrow = mask + b * S;

    // K staging geometry (global_load_lds, swizzled source)
    const int r0 = w * 8 + (lane >> 3);
    const int s0 = lane & 7;
    const int koff0 = r0 * QKV_N + (s0 ^ (r0 & 7)) * 8;           // halves
    const int koff1 = (32 + r0) * QKV_N + (s0 ^ ((32 + r0) & 7)) * 8;
    // V staging (reg-staged)
    const int srow = tid >> 3;          // 0..31
    const int scol = (tid & 7) * 8;     // 0,8,..,56

#define KSTAGE(KT, BUF)                                                        \
    {                                                                          \
        __builtin_amdgcn_global_load_lds(                                      \
            (as1_void*)(Kp + (size_t)(KT) * QKV_N + koff0),                    \
            (as3_void*)(&ksm[BUF][w * 512]), 16, 0, 0);                        \
        __builtin_amdgcn_global_load_lds(                                      \
            (as1_void*)(Kp + (size_t)(KT) * QKV_N + koff1),                    \
            (as3_void*)(&ksm[BUF][2048 + w * 512]), 16, 0, 0);                 \
    }

    // Q fragments, two q-groups (rows +0 and +64), pre-scaled
    const int qrow0 = qt * 128 + w * 16 + lc;
    const _Float16* Qp0 = qkv + (size_t)(b * S + qrow0) * QKV_N + h * HD;
    const _Float16* Qp1 = Qp0 + (size_t)64 * QKV_N;
    f16x8 qa0 = *(const f16x8*)(Qp0 + lg * 8);
    f16x8 qa1 = *(const f16x8*)(Qp0 + 32 + lg * 8);
    f16x8 qb0 = *(const f16x8*)(Qp1 + lg * 8);
    f16x8 qb1 = *(const f16x8*)(Qp1 + 32 + lg * 8);
    const _Float16 qs = (_Float16)(0.125f * 1.44269504f);
    qa0 *= qs; qa1 *= qs; qb0 *= qs; qb1 *= qs;

    // mask-bias table (all 1024 keys, once): valid ? -C2 : -1e9
#pragma unroll
    for (int i = 0; i < 4; ++i)
        mbias[i * 256 + tid] = mrow[i * 256 + tid] ? -C2 : -1e9f;

    // prologue: stage tile 0
    KSTAGE(0, 0)
    {
        const f16x8 gv0 = *(const f16x8*)(Vt + (size_t)srow * S + scol);
        const f16x8 gv1 = *(const f16x8*)(Vt + (size_t)(32 + srow) * S + scol);
        asm volatile("s_waitcnt vmcnt(0)" ::: "memory");
        *(f16x4*)&vsm[0][srow * 68 + scol] = ((const f16x4*)&gv0)[0];
        *(f16x4*)&vsm[0][srow * 68 + scol + 4] = ((const f16x4*)&gv0)[1];
        *(f16x4*)&vsm[0][(32 + srow) * 68 + scol] = ((const f16x4*)&gv1)[0];
        *(f16x4*)&vsm[0][(32 + srow) * 68 + scol + 4] = ((const f16x4*)&gv1)[1];
    }
    __syncthreads();

    f32x4 acca[4] = {}, accb[4] = {};
    float l_a = 0.f, l_b = 0.f;
    fp16x2 ones;
    ones[0] = (__fp16)1.0f; ones[1] = (__fp16)1.0f;

    for (int it = 0; it < S / 64; ++it) {
        const int cur = it & 1;
        const int ktn = (it + 1) * 64;
        const bool pref = (it + 1 < S / 64);
        f16x8 gv0, gv1;
        if (pref) {  // issue next tile's loads early (hide under compute)
            KSTAGE(ktn, cur ^ 1)
            gv0 = *(const f16x8*)(Vt + (size_t)srow * S + ktn + scol);
            gv1 = *(const f16x8*)(Vt + (size_t)(32 + srow) * S + ktn + scol);
        }

        __builtin_amdgcn_s_setprio(1);
#pragma unroll
        for (int t = 0; t < 4; ++t) {
            // swapped QK^T: S[key = t*16+4lg+j][q = lc]; C-init = mask bias
            const int krow = (t * 16 + lc) * 64;
            const f16x8 kfa =
                *(const f16x8*)&ksm[cur][krow + (lg ^ (lc & 7)) * 8];
            const f16x8 kfb =
                *(const f16x8*)&ksm[cur][krow + ((4 + lg) ^ (lc & 7)) * 8];
            const f32x4 mb = *(const f32x4*)&mbias[it * 64 + t * 16 + 4 * lg];

            f32x4 ca = mb, cb = mb;
            ca = __builtin_amdgcn_mfma_f32_16x16x32_f16(kfa, qa0, ca, 0, 0, 0);
            ca = __builtin_amdgcn_mfma_f32_16x16x32_f16(kfb, qa1, ca, 0, 0, 0);
            cb = __builtin_amdgcn_mfma_f32_16x16x32_f16(kfa, qb0, cb, 0, 0, 0);
            cb = __builtin_amdgcn_mfma_f32_16x16x32_f16(kfb, qb1, cb, 0, 0, 0);

            const auto ua0 = __builtin_amdgcn_cvt_pkrtz(EXP2(ca[0]), EXP2(ca[1]));
            const auto ua1 = __builtin_amdgcn_cvt_pkrtz(EXP2(ca[2]), EXP2(ca[3]));
            const auto ub0 = __builtin_amdgcn_cvt_pkrtz(EXP2(cb[0]), EXP2(cb[1]));
            const auto ub1 = __builtin_amdgcn_cvt_pkrtz(EXP2(cb[2]), EXP2(cb[3]));
            l_a = __builtin_amdgcn_fdot2(ua0, ones, l_a, false);
            l_a = __builtin_amdgcn_fdot2(ua1, ones, l_a, false);
            l_b = __builtin_amdgcn_fdot2(ub0, ones, l_b, false);
            l_b = __builtin_amdgcn_fdot2(ub1, ones, l_b, false);

            f16x4 pa, pb;
            pa[0] = (_Float16)ua0[0]; pa[1] = (_Float16)ua0[1];
            pa[2] = (_Float16)ua1[0]; pa[3] = (_Float16)ua1[1];
            pb[0] = (_Float16)ub0[0]; pb[1] = (_Float16)ub0[1];
            pb[2] = (_Float16)ub1[0]; pb[3] = (_Float16)ub1[1];

            // PV over this 16-key tile: 4 hd-groups of 16 (V frags shared)
#pragma unroll
            for (int g = 0; g < 4; ++g) {
                const f16x4 vf =
                    *(const f16x4*)&vsm[cur][(g * 16 + lc) * 68 + t * 16 + lg * 4];
                acca[g] = __builtin_amdgcn_mfma_f32_16x16x16f16(pa, vf, acca[g], 0, 0, 0);
                accb[g] = __builtin_amdgcn_mfma_f32_16x16x16f16(pb, vf, accb[g], 0, 0, 0);
            }
        }
        __builtin_amdgcn_s_setprio(0);

        if (pref) {  // K already landing in ksm[cur^1]; write V after drain
            asm volatile("s_waitcnt vmcnt(0)" ::: "memory");
            *(f16x4*)&vsm[cur ^ 1][srow * 68 + scol] = ((const f16x4*)&gv0)[0];
            *(f16x4*)&vsm[cur ^ 1][srow * 68 + scol + 4] = ((const f16x4*)&gv0)[1];
            *(f16x4*)&vsm[cur ^ 1][(32 + srow) * 68 + scol] = ((const f16x4*)&gv1)[0];
            *(f16x4*)&vsm[cur ^ 1][(32 + srow) * 68 + scol + 4] = ((const f16x4*)&gv1)[1];
        }
        __syncthreads();   // writes visible; all reads of buf[cur] done
    }
#undef KSTAGE

    // epilogue: reduce l across lg-groups, redistribute, normalize, write
    float la = l_a, lb = l_b;
    la += __shfl_xor(la, 16); la += __shfl_xor(la, 32);
    lb += __shfl_xor(lb, 16); lb += __shfl_xor(lb, 32);
    const float inva = la > 0.f ? 1.f / la : 0.f;
    const float invb = lb > 0.f ? 1.f / lb : 0.f;

#pragma unroll
    for (int j = 0; j < 4; ++j) {
        const int qin = 4 * lg + j;
        const float ija = __shfl(inva, qin);
        const float ijb = __shfl(invb, qin);
        const int qra = qt * 128 + w * 16 + qin;
        const int qrb = qra + 64;
        const float iqa = mrow[qra] ? ija : 0.f;
        const float iqb = mrow[qrb] ? ijb : 0.f;
        const size_t oa = ((size_t)(b * S + qra)) * D + h * HD;
        const size_t ob = ((size_t)(b * S + qrb)) * D + h * HD;
#pragma unroll
        for (int g = 0; g < 4; ++g) {
            ctx[oa + 16 * g + lc] = (_Float16)(acca[g][j] * iqa);
            ctx[ob + 16 * g + lc] = (_Float16)(accb[g][j] * iqb);
        }
    }
}

// -------------------------------------------------------------------------------
extern "C" void kernel_launch(void* const* d_in, const int* in_sizes, int n_in,
                              void* d_out, int out_size, void* d_ws, size_t ws_size,
                              hipStream_t stream) {
    const float* hidden = (const float*)d_in[0];
    const unsigned char* maskraw = (const unsigned char*)d_in[1];
    const float* qkv_w = (const float*)d_in[2];
    const float* qkv_b = (const float*)d_in[3];
    const float* proj_w = (const float*)d_in[4];
    const float* proj_b = (const float*)d_in[5];
    float* out = (float*)d_out;

    char* ws = (char*)d_ws;
    size_t off = 0;
    int* maskN = (int*)(ws + off);            off += (size_t)NTOK * 4;
    _Float16* hid16 = (_Float16*)(ws + off);  off += (size_t)NTOK * D * 2;
    _Float16* qkvw16 = (_Float16*)(ws + off); off += (size_t)QKV_N * D * 2;
    _Float16* projw16 = (_Float16*)(ws + off); off += (size_t)D * D * 2;
    _Float16* qkv16 = (_Float16*)(ws + off);  off += (size_t)NTOK * QKV_N * 2;
    _Float16* vt = (_Float16*)(ws + off);     off += (size_t)NTOK * D * 2;
    _Float16* ctx16 = (_Float16*)(ws + off);  off += (size_t)NTOK * D * 2;

    normalize_mask_kernel<<<1, 256, 0, stream>>>(maskraw, maskN, NTOK);

    const int n0 = NTOK * D / 4, n1 = QKV_N * D / 4, n2 = D * D / 4;
    cvt_all_f16<<<(n0 + n1 + n2 + 255) / 256, 256, 0, stream>>>(
        hidden, hid16, n0, qkv_w, qkvw16, n1, proj_w, projw16, n2);

    // qkv GEMM (+fused V-transpose): 128*18 = 2304 blocks
    gemm16<1><<<dim3(2304), 256, 0, stream>>>(
        hid16, qkvw16, qkv_b, nullptr, QKV_N, nullptr, qkv16, vt);

    attn_kernel<<<dim3(B * H * (S / 128)), 256, 0, stream>>>(qkv16, vt, maskN, ctx16);

    // proj GEMM: 128*6 = 768 blocks
    gemm16<0><<<dim3(768), 256, 0, stream>>>(
        ctx16, projw16, proj_b, maskN, D, out, nullptr, nullptr);
}

// Round 13
// 206.739 us; speedup vs baseline: 1.2280x; 1.0044x over previous
//
#include <hip/hip_runtime.h>
#include <cstdint>
#include <cstddef>

#define B 16
#define S 1024
#define D 768
#define H 12
#define HD 64
#define NTOK (B * S)        // 16384
#define QKV_N (3 * D)       // 2304
#define SCALE 0.125f        // 64^-0.5
#define C2 2.88539008f      // 2.0 * log2(e): fixed softmax shift (nat-log C=2)
#define GK 768              // GEMM contraction dim (both GEMMs)
#define NT_K 12             // GK / 64

typedef _Float16 f16x8 __attribute__((ext_vector_type(8)));
typedef _Float16 f16x4 __attribute__((ext_vector_type(4)));
typedef __fp16 fp16x2 __attribute__((ext_vector_type(2)));
typedef float f32x4 __attribute__((ext_vector_type(4)));

typedef __attribute__((address_space(3))) void as3_void;
typedef const __attribute__((address_space(1))) void as1_void;

#if defined(__has_builtin)
#if __has_builtin(__builtin_amdgcn_exp2f)
#define EXP2(x) __builtin_amdgcn_exp2f(x)
#else
#define EXP2(x) exp2f(x)
#endif
#else
#define EXP2(x) exp2f(x)
#endif

// ---------------- mask normalization (bool-byte vs int32 agnostic) -------------
__global__ __launch_bounds__(256) void normalize_mask_kernel(
    const unsigned char* __restrict__ raw, int* __restrict__ outm, int n) {
    __shared__ int s_isbyte;
    const int tid = threadIdx.x;
    if (tid == 0) s_isbyte = 0;
    __syncthreads();
    int found = 0;
    for (int i = tid; i < n; i += 256) {
        if ((i & 3) != 0 && raw[i] != 0) found = 1;
    }
    if (found) atomicOr(&s_isbyte, 1);
    __syncthreads();
    const int isbyte = s_isbyte;
    if (isbyte) {
        for (int i = tid; i < n; i += 256) outm[i] = raw[i] ? 1 : 0;
    } else {
        const int* r32 = (const int*)raw;
        for (int i = tid; i < n; i += 256) outm[i] = r32[i] ? 1 : 0;
    }
}

// ---------------- f32 -> f16 conversion (3 tensors, one launch) ----------------
__global__ __launch_bounds__(256) void cvt_all_f16(
    const float* __restrict__ in0, _Float16* __restrict__ out0, int n0,
    const float* __restrict__ in1, _Float16* __restrict__ out1, int n1,
    const float* __restrict__ in2, _Float16* __restrict__ out2, int n2) {
    int i = blockIdx.x * 256 + threadIdx.x;
    const float* in;
    _Float16* out;
    if (i < n0) { in = in0; out = out0; }
    else if (i < n0 + n1) { i -= n0; in = in1; out = out1; }
    else { i -= n0 + n1; in = in2; out = out2; if (i >= n2) return; }
    const float4 v = ((const float4*)in)[i];
    f16x4 o;
    o[0] = (_Float16)v.x; o[1] = (_Float16)v.y;
    o[2] = (_Float16)v.z; o[3] = (_Float16)v.w;
    ((f16x4*)out)[i] = o;
}

// ---------------- f16 MFMA GEMM: C[m,n] = sum_k A[m,k]*W[n,k] + bias[n] --------
// 128x128 tile, BK=64, 256 threads = 4 waves (2x2 of 64x64).
// Double-buffered LDS + counted vmcnt(8) across raw s_barrier.
// XOR swizzle (slot ^= row&7) on global source AND ds_read addr (conflict-free).
// MODE 1 (QKV): Q,K column-blocks (bn<1536) -> row-major f16 qkv16;
//               V column-blocks (bn>=1536, never straddle) -> transposed into
//               vt[B,H,64,S] via post-loop LDS transpose (smem reuse).
// MODE 0 (proj): f32 out + rowmask zeroing.
template <int MODE>
__global__ __launch_bounds__(256, 2) void gemm16(
    const _Float16* __restrict__ A, const _Float16* __restrict__ Wm,
    const float* __restrict__ bias, const int* __restrict__ rowmask,
    int N, float* __restrict__ outf, _Float16* __restrict__ outh,
    _Float16* __restrict__ vtb) {
    __shared__ _Float16 smem[32768];   // 64 KB: As[2]=smem+buf*8192, Bs[2]=+16384

    const int tid = threadIdx.x;
    const int w = tid >> 6, l = tid & 63;
    const int wm = (w >> 1) * 64, wn = (w & 1) * 64;
    const int lg = l >> 4, lc = l & 15;

    // XCD-aware decode: bid%8 = XCD; per XCD a 16-row M-stripe, N-major inside.
    const int bid = blockIdx.x;
    const int xcd = bid & 7;
    const int idx = bid >> 3;
    const int bn = (idx >> 4) * 128;
    const int bm = (xcd * 16 + (idx & 15)) * 128;

    f32x4 acc[4][4] = {};

#define STAGE(T, BUF)                                                           \
    {                                                                           \
        const int kt_ = (T) * 64;                                               \
        _Pragma("unroll")                                                       \
        for (int i_ = 0; i_ < 4; ++i_) {                                        \
            const int ci_ = (w << 2) + i_;       /* 0..15 */                    \
            const int r_ = (ci_ << 3) + (l >> 3);                               \
            const int c16_ = (l & 7) ^ (r_ & 7);                                \
            __builtin_amdgcn_global_load_lds(                                   \
                (as1_void*)(A + (size_t)(bm + r_) * GK + kt_ + c16_ * 8),       \
                (as3_void*)(smem + (BUF) * 8192 + ci_ * 512), 16, 0, 0);        \
            __builtin_amdgcn_global_load_lds(                                   \
                (as1_void*)(Wm + (size_t)(bn + r_) * GK + kt_ + c16_ * 8),      \
                (as3_void*)(smem + 16384 + (BUF) * 8192 + ci_ * 512), 16, 0, 0);\
        }                                                                       \
    }

    STAGE(0, 0)

    for (int t = 0; t < NT_K; ++t) {
        const int cur = t & 1;
        if (t + 1 < NT_K) {
            STAGE(t + 1, cur ^ 1)
            asm volatile("s_waitcnt vmcnt(8)" ::: "memory");
        } else {
            asm volatile("s_waitcnt vmcnt(0)" ::: "memory");
        }
        __builtin_amdgcn_s_barrier();   // buf[cur] populated & visible

        const _Float16* sA = smem + cur * 8192;
        const _Float16* sB = smem + 16384 + cur * 8192;
        __builtin_amdgcn_s_setprio(1);
#pragma unroll
        for (int kk = 0; kk < 2; ++kk) {
            const int c16 = ((kk << 2) + lg) ^ (lc & 7);
            f16x8 af[4], bf[4];
#pragma unroll
            for (int ni = 0; ni < 4; ++ni)
                bf[ni] = *(const f16x8*)&sB[(wn + ni * 16 + lc) * 64 + c16 * 8];
#pragma unroll
            for (int mi = 0; mi < 4; ++mi)
                af[mi] = *(const f16x8*)&sA[(wm + mi * 16 + lc) * 64 + c16 * 8];
#pragma unroll
            for (int mi = 0; mi < 4; ++mi)
#pragma unroll
                for (int ni = 0; ni < 4; ++ni)
                    acc[mi][ni] = __builtin_amdgcn_mfma_f32_16x16x32_f16(
                        af[mi], bf[ni], acc[mi][ni], 0, 0, 0);
        }
        __builtin_amdgcn_s_setprio(0);
        __builtin_amdgcn_s_barrier();   // all waves done reading buf[cur]
    }
#undef STAGE

    float bs[4];
#pragma unroll
    for (int ni = 0; ni < 4; ++ni) bs[ni] = bias[bn + wn + ni * 16 + lc];

    if (MODE == 1) {
        if (bn < 1536) {
            // Q,K: row-major f16
#pragma unroll
            for (int mi = 0; mi < 4; ++mi) {
#pragma unroll
                for (int j = 0; j < 4; ++j) {
                    const int m = bm + wm + mi * 16 + lg * 4 + j;
#pragma unroll
                    for (int ni = 0; ni < 4; ++ni) {
                        const int col = bn + wn + ni * 16 + lc;
                        outh[(size_t)m * N + col] =
                            (_Float16)(acc[mi][ni][j] + bs[ni]);
                    }
                }
            }
        } else {
            // V: transpose via LDS (smem reuse; [128 col][136] stride)
#pragma unroll
            for (int mi = 0; mi < 4; ++mi) {
#pragma unroll
                for (int ni = 0; ni < 4; ++ni) {
                    f16x4 v4;
#pragma unroll
                    for (int j = 0; j < 4; ++j)
                        v4[j] = (_Float16)(acc[mi][ni][j] + bs[ni]);
                    const int nl = wn + ni * 16 + lc;
                    const int ml = wm + mi * 16 + lg * 4;
                    *(f16x4*)&smem[nl * 136 + ml] = v4;
                }
            }
            __syncthreads();
            const int r = tid >> 1;            // local col 0..127 (hd dim)
            const int c0 = (tid & 1) * 64;     // token sub-block
            const int col0 = bn - 1536 + r;    // 0..767
            const int hh = col0 >> 6, hd = col0 & 63;
            const int bb = bm >> 10;
            const int s0 = (bm & 1023) + c0;
            _Float16* dst = vtb + ((size_t)(bb * H + hh) * HD + hd) * S + s0;
#pragma unroll
            for (int e = 0; e < 8; ++e)
                *(f16x8*)(dst + e * 8) = *(const f16x8*)&smem[r * 136 + c0 + e * 8];
        }
    } else {
#pragma unroll
        for (int mi = 0; mi < 4; ++mi) {
#pragma unroll
            for (int j = 0; j < 4; ++j) {
                const int m = bm + wm + mi * 16 + lg * 4 + j;
                const int mv = rowmask[m];
#pragma unroll
                for (int ni = 0; ni < 4; ++ni) {
                    const int col = bn + wn + ni * 16 + lc;
                    outf[(size_t)m * N + col] = mv ? acc[mi][ni][j] + bs[ni] : 0.f;
                }
            }
        }
    }
}

// ---------------- flash attention: swapped QK^T, register-resident P ----------
// grid: B*H*(S/256) = 768 = 3 blocks/CU exactly (zero tail), XCD-grouped.
// QBLK=256: each wave owns FOUR 16-row q-groups — every K/V fragment read,
// barrier, and staging op amortized 4x. K AND V staged via global_load_lds
// into linear [64][64] with 16B XOR swizzle on global source + ds_read addr
// (conflict-free / 2-way-free). Mask bias as MFMA C-init; fdot2 row-sums.
__global__ __launch_bounds__(256, 3) void attn_kernel(
    const _Float16* __restrict__ qkv, const _Float16* __restrict__ vtb,
    const int* __restrict__ mask, _Float16* __restrict__ ctx) {
    __shared__ _Float16 ksm[2][64 * 64];   // 16 KB
    __shared__ _Float16 vsm[2][64 * 64];   // 16 KB
    __shared__ float mbias[S];             // 4 KB

    const int blk = blockIdx.x;
    // XCD grouping: 768 blocks = 8 xcd * 24 bh * 4 qt
    const int xcd = blk & 7;
    const int idx = blk >> 3;
    const int bh_ = xcd * 24 + (idx >> 2);
    const int qt = idx & 3;
    const int h = bh_ % H;
    const int b = bh_ / H;
    const int tid = threadIdx.x;
    const int w = tid >> 6, lane = tid & 63;
    const int lg = lane >> 4, lc = lane & 15;

    const size_t bh = (size_t)(b * H + h);
    const _Float16* Kp = qkv + (size_t)(b * S) * QKV_N + D + h * HD; // +row*2304
    const _Float16* Vt = vtb + bh * HD * S;
    const int* mrow = mask + b * S;

    // DMA staging geometry: instr covers rows r0 (and r0+32); LDS linear dest,
    // global source col16 XOR-swizzled by row. (32+r0)&7 == r0&7.
    const int r0 = w * 8 + (lane >> 3);
    const int swz8 = ((lane & 7) ^ (r0 & 7)) * 8;
    const int koff0 = r0 * QKV_N + swz8;
    const int koff1 = (32 + r0) * QKV_N + swz8;
    const int voff0 = r0 * S + swz8;
    const int voff1 = (32 + r0) * S + swz8;

#define STAGE(KT, BUF)                                                         \
    {                                                                          \
        __builtin_amdgcn_global_load_lds(                                      \
            (as1_void*)(Kp + (size_t)(KT) * QKV_N + koff0),                    \
            (as3_void*)(&ksm[BUF][w * 512]), 16, 0, 0);                        \
        __builtin_amdgcn_global_load_lds(                                      \
            (as1_void*)(Kp + (size_t)(KT) * QKV_N + koff1),                    \
            (as3_void*)(&ksm[BUF][2048 + w * 512]), 16, 0, 0);                 \
        __builtin_amdgcn_global_load_lds(                                      \
            (as1_void*)(Vt + (size_t)(KT) + voff0),                            \
            (as3_void*)(&vsm[BUF][w * 512]), 16, 0, 0);                        \
        __builtin_amdgcn_global_load_lds(                                      \
            (as1_void*)(Vt + (size_t)(KT) + voff1),                            \
            (as3_void*)(&vsm[BUF][2048 + w * 512]), 16, 0, 0);                 \
    }

    // Q fragments: four q-groups (rows +0,+64,+128,+192), pre-scaled
    const int qbase = qt * 256 + w * 16 + lc;
    const _Float16 qs = (_Float16)(0.125f * 1.44269504f);
    f16x8 qf[4][2];
#pragma unroll
    for (int qg = 0; qg < 4; ++qg) {
        const _Float16* Qp =
            qkv + (size_t)(b * S + qbase + qg * 64) * QKV_N + h * HD;
        qf[qg][0] = *(const f16x8*)(Qp + lg * 8);
        qf[qg][1] = *(const f16x8*)(Qp + 32 + lg * 8);
        qf[qg][0] *= qs;
        qf[qg][1] *= qs;
    }

    // mask-bias table (all 1024 keys, once): valid ? -C2 : -1e9
#pragma unroll
    for (int i = 0; i < 4; ++i)
        mbias[i * 256 + tid] = mrow[i * 256 + tid] ? -C2 : -1e9f;

    STAGE(0, 0)
    __syncthreads();   // implicit vmcnt(0) lgkmcnt(0): tile 0 + mbias ready

    f32x4 acc[4][4] = {};
    float lsum[4] = {0.f, 0.f, 0.f, 0.f};
    fp16x2 ones;
    ones[0] = (__fp16)1.0f; ones[1] = (__fp16)1.0f;

    for (int it = 0; it < S / 64; ++it) {
        const int cur = it & 1;
        if (it + 1 < S / 64) STAGE((it + 1) * 64, cur ^ 1)

        __builtin_amdgcn_s_setprio(1);
#pragma unroll
        for (int t = 0; t < 4; ++t) {
            // swapped QK^T: S[key = t*16+4lg+j][q = lc]; C-init = mask bias
            const int krow = (t * 16 + lc) * 64;
            const f16x8 kfa =
                *(const f16x8*)&ksm[cur][krow + (lg ^ (lc & 7)) * 8];
            const f16x8 kfb =
                *(const f16x8*)&ksm[cur][krow + ((4 + lg) ^ (lc & 7)) * 8];
            const f32x4 mb = *(const f32x4*)&mbias[it * 64 + t * 16 + 4 * lg];

            f16x4 pp[4];
#pragma unroll
            for (int qg = 0; qg < 4; ++qg) {
                f32x4 c = mb;
                c = __builtin_amdgcn_mfma_f32_16x16x32_f16(kfa, qf[qg][0], c, 0, 0, 0);
                c = __builtin_amdgcn_mfma_f32_16x16x32_f16(kfb, qf[qg][1], c, 0, 0, 0);
                const auto u0 = __builtin_amdgcn_cvt_pkrtz(EXP2(c[0]), EXP2(c[1]));
                const auto u1 = __builtin_amdgcn_cvt_pkrtz(EXP2(c[2]), EXP2(c[3]));
                lsum[qg] = __builtin_amdgcn_fdot2(u0, ones, lsum[qg], false);
                lsum[qg] = __builtin_amdgcn_fdot2(u1, ones, lsum[qg], false);
                pp[qg][0] = (_Float16)u0[0]; pp[qg][1] = (_Float16)u0[1];
                pp[qg][2] = (_Float16)u1[0]; pp[qg][3] = (_Float16)u1[1];
            }

            // PV over this 16-key tile: 4 hd-groups; V frags shared by 4 qg
#pragma unroll
            for (int g = 0; g < 4; ++g) {
                const int vrow = (g * 16 + lc) * 64;
                const f16x4 vf = *(const f16x4*)&vsm[cur][
                    vrow + (((2 * t + (lg >> 1)) ^ (lc & 7)) << 3) + (lg & 1) * 4];
#pragma unroll
                for (int qg = 0; qg < 4; ++qg)
                    acc[qg][g] = __builtin_amdgcn_mfma_f32_16x16x16f16(
                        pp[qg], vf, acc[qg][g], 0, 0, 0);
            }
        }
        __builtin_amdgcn_s_setprio(0);
        __syncthreads();   // drains DMA (vmcnt) + orders buffer reuse
    }
#undef STAGE

    // epilogue: reduce l across lg-groups, redistribute, normalize, write
#pragma unroll
    for (int qg = 0; qg < 4; ++qg) {
        float l = lsum[qg];
        l += __shfl_xor(l, 16);
        l += __shfl_xor(l, 32);
        const float inv = l > 0.f ? 1.f / l : 0.f;
#pragma unroll
        for (int j = 0; j < 4; ++j) {
            const int qin = 4 * lg + j;
            const float ij = __shfl(inv, qin);
            const int qr = qt * 256 + qg * 64 + w * 16 + qin;
            const float iq = mrow[qr] ? ij : 0.f;
            const size_t o = ((size_t)(b * S + qr)) * D + h * HD;
#pragma unroll
            for (int g = 0; g < 4; ++g)
                ctx[o + 16 * g + lc] = (_Float16)(acc[qg][g][j] * iq);
        }
    }
}

// -------------------------------------------------------------------------------
extern "C" void kernel_launch(void* const* d_in, const int* in_sizes, int n_in,
                              void* d_out, int out_size, void* d_ws, size_t ws_size,
                              hipStream_t stream) {
    const float* hidden = (const float*)d_in[0];
    const unsigned char* maskraw = (const unsigned char*)d_in[1];
    const float* qkv_w = (const float*)d_in[2];
    const float* qkv_b = (const float*)d_in[3];
    const float* proj_w = (const float*)d_in[4];
    const float* proj_b = (const float*)d_in[5];
    float* out = (float*)d_out;

    char* ws = (char*)d_ws;
    size_t off = 0;
    int* maskN = (int*)(ws + off);            off += (size_t)NTOK * 4;
    _Float16* hid16 = (_Float16*)(ws + off);  off += (size_t)NTOK * D * 2;
    _Float16* qkvw16 = (_Float16*)(ws + off); off += (size_t)QKV_N * D * 2;
    _Float16* projw16 = (_Float16*)(ws + off); off += (size_t)D * D * 2;
    _Float16* qkv16 = (_Float16*)(ws + off);  off += (size_t)NTOK * QKV_N * 2;
    _Float16* vt = (_Float16*)(ws + off);     off += (size_t)NTOK * D * 2;
    _Float16* ctx16 = (_Float16*)(ws + off);  off += (size_t)NTOK * D * 2;

    normalize_mask_kernel<<<1, 256, 0, stream>>>(maskraw, maskN, NTOK);

    const int n0 = NTOK * D / 4, n1 = QKV_N * D / 4, n2 = D * D / 4;
    cvt_all_f16<<<(n0 + n1 + n2 + 255) / 256, 256, 0, stream>>>(
        hidden, hid16, n0, qkv_w, qkvw16, n1, proj_w, projw16, n2);

    // qkv GEMM (+fused V-transpose): 128*18 = 2304 blocks
    gemm16<1><<<dim3(2304), 256, 0, stream>>>(
        hid16, qkvw16, qkv_b, nullptr, QKV_N, nullptr, qkv16, vt);

    attn_kernel<<<dim3(B * H * (S / 256)), 256, 0, stream>>>(qkv16, vt, maskN, ctx16);

    // proj GEMM: 128*6 = 768 blocks
    gemm16<0><<<dim3(768), 256, 0, stream>>>(
        ctx16, projw16, proj_b, maskN, D, out, nullptr, nullptr);
}

// Round 16
// 200.079 us; speedup vs baseline: 1.2689x; 1.0333x over previous
//
#include <hip/hip_runtime.h>
#include <cstdint>
#include <cstddef>

#define B 16
#define S 1024
#define D 768
#define H 12
#define HD 64
#define NTOK (B * S)        // 16384
#define QKV_N (3 * D)       // 2304
#define SCALE 0.125f        // 64^-0.5
#define C2 2.88539008f      // 2.0 * log2(e): fixed softmax shift (nat-log C=2)
#define GK 768              // GEMM contraction dim (both GEMMs)
#define NT_K 12             // GK / 64

typedef _Float16 f16x8 __attribute__((ext_vector_type(8)));
typedef _Float16 f16x4 __attribute__((ext_vector_type(4)));
typedef __fp16 fp16x2 __attribute__((ext_vector_type(2)));
typedef float f32x4 __attribute__((ext_vector_type(4)));

typedef __attribute__((address_space(3))) void as3_void;
typedef const __attribute__((address_space(1))) void as1_void;

#if defined(__has_builtin)
#if __has_builtin(__builtin_amdgcn_exp2f)
#define EXP2(x) __builtin_amdgcn_exp2f(x)
#else
#define EXP2(x) exp2f(x)
#endif
#else
#define EXP2(x) exp2f(x)
#endif

// s_barrier WITH compiler memory fence.
#define BARRIER() asm volatile("s_barrier" ::: "memory")

// ---------------- mask normalization (bool-byte vs int32 agnostic) -------------
__global__ __launch_bounds__(256) void normalize_mask_kernel(
    const unsigned char* __restrict__ raw, int* __restrict__ outm, int n) {
    __shared__ int s_isbyte;
    const int tid = threadIdx.x;
    if (tid == 0) s_isbyte = 0;
    __syncthreads();
    int found = 0;
    for (int i = tid; i < n; i += 256) {
        if ((i & 3) != 0 && raw[i] != 0) found = 1;
    }
    if (found) atomicOr(&s_isbyte, 1);
    __syncthreads();
    const int isbyte = s_isbyte;
    if (isbyte) {
        for (int i = tid; i < n; i += 256) outm[i] = raw[i] ? 1 : 0;
    } else {
        const int* r32 = (const int*)raw;
        for (int i = tid; i < n; i += 256) outm[i] = r32[i] ? 1 : 0;
    }
}

// ---------------- f32 -> f16 conversion (3 tensors, one launch) ----------------
__global__ __launch_bounds__(256) void cvt_all_f16(
    const float* __restrict__ in0, _Float16* __restrict__ out0, int n0,
    const float* __restrict__ in1, _Float16* __restrict__ out1, int n1,
    const float* __restrict__ in2, _Float16* __restrict__ out2, int n2) {
    int i = blockIdx.x * 256 + threadIdx.x;
    const float* in;
    _Float16* out;
    if (i < n0) { in = in0; out = out0; }
    else if (i < n0 + n1) { i -= n0; in = in1; out = out1; }
    else { i -= n0 + n1; in = in2; out = out2; if (i >= n2) return; }
    const float4 v = ((const float4*)in)[i];
    f16x4 o;
    o[0] = (_Float16)v.x; o[1] = (_Float16)v.y;
    o[2] = (_Float16)v.z; o[3] = (_Float16)v.w;
    ((f16x4*)out)[i] = o;
}

// ---------------- f16 MFMA GEMM: C[m,n] = sum_k A[m,k]*W[n,k] + bias[n] --------
// 128x128 tile, BK=64, 256 threads = 4 waves (2x2 of 64x64).
// Double-buffered LDS + counted vmcnt(8) across fenced s_barrier.
// XOR swizzle (slot ^= row&7) on global source AND ds_read addr (conflict-free).
// MODE 1 (QKV): Q,K column-blocks (bn<1536) -> row-major f16 qkv16;
//               V column-blocks (bn>=1536, never straddle) -> transposed into
//               vt[B,H,64,S] via post-loop LDS transpose (smem reuse).
// MODE 0 (proj): f32 out + rowmask zeroing.
template <int MODE>
__global__ __launch_bounds__(256, 2) void gemm16(
    const _Float16* __restrict__ A, const _Float16* __restrict__ Wm,
    const float* __restrict__ bias, const int* __restrict__ rowmask,
    int N, float* __restrict__ outf, _Float16* __restrict__ outh,
    _Float16* __restrict__ vtb) {
    __shared__ _Float16 smem[32768];   // 64 KB: As[2]=smem+buf*8192, Bs[2]=+16384

    const int tid = threadIdx.x;
    const int w = tid >> 6, l = tid & 63;
    const int wm = (w >> 1) * 64, wn = (w & 1) * 64;
    const int lg = l >> 4, lc = l & 15;

    // XCD-aware decode: bid%8 = XCD; per XCD a 16-row M-stripe, N-major inside.
    const int bid = blockIdx.x;
    const int xcd = bid & 7;
    const int idx = bid >> 3;
    const int bn = (idx >> 4) * 128;
    const int bm = (xcd * 16 + (idx & 15)) * 128;

    f32x4 acc[4][4] = {};

#define STAGE(T, BUF)                                                           \
    {                                                                           \
        const int kt_ = (T) * 64;                                               \
        _Pragma("unroll")                                                       \
        for (int i_ = 0; i_ < 4; ++i_) {                                        \
            const int ci_ = (w << 2) + i_;       /* 0..15 */                    \
            const int r_ = (ci_ << 3) + (l >> 3);                               \
            const int c16_ = (l & 7) ^ (r_ & 7);                                \
            __builtin_amdgcn_global_load_lds(                                   \
                (as1_void*)(A + (size_t)(bm + r_) * GK + kt_ + c16_ * 8),       \
                (as3_void*)(smem + (BUF) * 8192 + ci_ * 512), 16, 0, 0);        \
            __builtin_amdgcn_global_load_lds(                                   \
                (as1_void*)(Wm + (size_t)(bn + r_) * GK + kt_ + c16_ * 8),      \
                (as3_void*)(smem + 16384 + (BUF) * 8192 + ci_ * 512), 16, 0, 0);\
        }                                                                       \
    }

    STAGE(0, 0)

    for (int t = 0; t < NT_K; ++t) {
        const int cur = t & 1;
        if (t + 1 < NT_K) {
            STAGE(t + 1, cur ^ 1)
            asm volatile("s_waitcnt vmcnt(8)" ::: "memory");
        } else {
            asm volatile("s_waitcnt vmcnt(0)" ::: "memory");
        }
        BARRIER();   // buf[cur] populated & visible

        const _Float16* sA = smem + cur * 8192;
        const _Float16* sB = smem + 16384 + cur * 8192;
        __builtin_amdgcn_s_setprio(1);
#pragma unroll
        for (int kk = 0; kk < 2; ++kk) {
            const int c16 = ((kk << 2) + lg) ^ (lc & 7);
            f16x8 af[4], bf[4];
#pragma unroll
            for (int ni = 0; ni < 4; ++ni)
                bf[ni] = *(const f16x8*)&sB[(wn + ni * 16 + lc) * 64 + c16 * 8];
#pragma unroll
            for (int mi = 0; mi < 4; ++mi)
                af[mi] = *(const f16x8*)&sA[(wm + mi * 16 + lc) * 64 + c16 * 8];
#pragma unroll
            for (int mi = 0; mi < 4; ++mi)
#pragma unroll
                for (int ni = 0; ni < 4; ++ni)
                    acc[mi][ni] = __builtin_amdgcn_mfma_f32_16x16x32_f16(
                        af[mi], bf[ni], acc[mi][ni], 0, 0, 0);
        }
        __builtin_amdgcn_s_setprio(0);
        BARRIER();   // all waves done reading buf[cur]
    }
#undef STAGE

    float bs[4];
#pragma unroll
    for (int ni = 0; ni < 4; ++ni) bs[ni] = bias[bn + wn + ni * 16 + lc];

    if (MODE == 1) {
        if (bn < 1536) {
            // Q,K: row-major f16
#pragma unroll
            for (int mi = 0; mi < 4; ++mi) {
#pragma unroll
                for (int j = 0; j < 4; ++j) {
                    const int m = bm + wm + mi * 16 + lg * 4 + j;
#pragma unroll
                    for (int ni = 0; ni < 4; ++ni) {
                        const int col = bn + wn + ni * 16 + lc;
                        outh[(size_t)m * N + col] =
                            (_Float16)(acc[mi][ni][j] + bs[ni]);
                    }
                }
            }
        } else {
            // V: transpose via LDS (smem reuse; [128 col][136] stride)
#pragma unroll
            for (int mi = 0; mi < 4; ++mi) {
#pragma unroll
                for (int ni = 0; ni < 4; ++ni) {
                    f16x4 v4;
#pragma unroll
                    for (int j = 0; j < 4; ++j)
                        v4[j] = (_Float16)(acc[mi][ni][j] + bs[ni]);
                    const int nl = wn + ni * 16 + lc;
                    const int ml = wm + mi * 16 + lg * 4;
                    *(f16x4*)&smem[nl * 136 + ml] = v4;
                }
            }
            __syncthreads();
            const int r = tid >> 1;            // local col 0..127 (hd dim)
            const int c0 = (tid & 1) * 64;     // token sub-block
            const int col0 = bn - 1536 + r;    // 0..767
            const int hh = col0 >> 6, hd = col0 & 63;
            const int bb = bm >> 10;
            const int s0 = (bm & 1023) + c0;
            _Float16* dst = vtb + ((size_t)(bb * H + hh) * HD + hd) * S + s0;
#pragma unroll
            for (int e = 0; e < 8; ++e)
                *(f16x8*)(dst + e * 8) = *(const f16x8*)&smem[r * 136 + c0 + e * 8];
        }
    } else {
#pragma unroll
        for (int mi = 0; mi < 4; ++mi) {
#pragma unroll
            for (int j = 0; j < 4; ++j) {
                const int m = bm + wm + mi * 16 + lg * 4 + j;
                const int mv = rowmask[m];
#pragma unroll
                for (int ni = 0; ni < 4; ++ni) {
                    const int col = bn + wn + ni * 16 + lc;
                    outf[(size_t)m * N + col] = mv ? acc[mi][ni][j] + bs[ni] : 0.f;
                }
            }
        }
    }
}

// ---------------- flash attention: swapped QK^T, register-resident P ----------
// grid: B*H*(S/256) = 768 = 3 blocks/CU exactly, XCD-grouped. QBLK=256.
// THREE K/V LDS buffers, depth-2 DMA pipeline, counted vmcnt, fenced barriers:
// [STAGE(it+2) -> gate -> barrier -> compute(it) -> barrier].
// STAGE macro takes TILE INDEX (x64 internally) — r14/r15 bug was the prologue
// passing tile index to a raw-offset macro (staged keys 1..64 instead of 64..127).
__global__ __launch_bounds__(256, 3) void attn_kernel(
    const _Float16* __restrict__ qkv, const _Float16* __restrict__ vtb,
    const int* __restrict__ mask, _Float16* __restrict__ ctx) {
    __shared__ _Float16 ksm[3][64 * 64];   // 24 KB
    __shared__ _Float16 vsm[3][64 * 64];   // 24 KB
    __shared__ float mbias[S];             // 4 KB

    const int blk = blockIdx.x;
    // XCD grouping: 768 blocks = 8 xcd * 24 bh * 4 qt
    const int xcd = blk & 7;
    const int idx = blk >> 3;
    const int bh_ = xcd * 24 + (idx >> 2);
    const int qt = idx & 3;
    const int h = bh_ % H;
    const int b = bh_ / H;
    const int tid = threadIdx.x;
    const int w = tid >> 6, lane = tid & 63;
    const int lg = lane >> 4, lc = lane & 15;

    const size_t bh = (size_t)(b * H + h);
    const _Float16* Kp = qkv + (size_t)(b * S) * QKV_N + D + h * HD; // +row*2304
    const _Float16* Vt = vtb + bh * HD * S;
    const int* mrow = mask + b * S;

    // DMA staging geometry: instr covers rows r0 (and r0+32); LDS linear dest,
    // global source col16 XOR-swizzled by row. (32+r0)&7 == r0&7.
    const int r0 = w * 8 + (lane >> 3);
    const int swz8 = ((lane & 7) ^ (r0 & 7)) * 8;
    const int koff0 = r0 * QKV_N + swz8;
    const int koff1 = (32 + r0) * QKV_N + swz8;
    const int voff0 = r0 * S + swz8;
    const int voff1 = (32 + r0) * S + swz8;

// T = tile index (keys T*64 .. T*64+63)
#define STAGE(T, BUF)                                                          \
    {                                                                          \
        const int kt_ = (T) * 64;                                              \
        __builtin_amdgcn_global_load_lds(                                      \
            (as1_void*)(Kp + (size_t)kt_ * QKV_N + koff0),                     \
            (as3_void*)(&ksm[BUF][w * 512]), 16, 0, 0);                        \
        __builtin_amdgcn_global_load_lds(                                      \
            (as1_void*)(Kp + (size_t)kt_ * QKV_N + koff1),                     \
            (as3_void*)(&ksm[BUF][2048 + w * 512]), 16, 0, 0);                 \
        __builtin_amdgcn_global_load_lds(                                      \
            (as1_void*)(Vt + (size_t)kt_ + voff0),                            \
            (as3_void*)(&vsm[BUF][w * 512]), 16, 0, 0);                        \
        __builtin_amdgcn_global_load_lds(                                      \
            (as1_void*)(Vt + (size_t)kt_ + voff1),                            \
            (as3_void*)(&vsm[BUF][2048 + w * 512]), 16, 0, 0);                 \
    }

    // Q fragments: four q-groups (rows +0,+64,+128,+192), pre-scaled
    const int qbase = qt * 256 + w * 16 + lc;
    const _Float16 qs = (_Float16)(0.125f * 1.44269504f);
    f16x8 qf[4][2];
#pragma unroll
    for (int qg = 0; qg < 4; ++qg) {
        const _Float16* Qp =
            qkv + (size_t)(b * S + qbase + qg * 64) * QKV_N + h * HD;
        qf[qg][0] = *(const f16x8*)(Qp + lg * 8);
        qf[qg][1] = *(const f16x8*)(Qp + 32 + lg * 8);
        qf[qg][0] *= qs;
        qf[qg][1] *= qs;
    }

    // mask-bias table (all 1024 keys, once): valid ? -C2 : -1e9
#pragma unroll
    for (int i = 0; i < 4; ++i)
        mbias[i * 256 + tid] = mrow[i * 256 + tid] ? -C2 : -1e9f;

    // prologue: depth-2 fill (tiles 0 and 1)
    STAGE(0, 0)
    STAGE(1, 1)

    f32x4 acc[4][4] = {};
    float lsum[4] = {0.f, 0.f, 0.f, 0.f};
    fp16x2 ones;
    ones[0] = (__fp16)1.0f; ones[1] = (__fp16)1.0f;

    int cur = 0;
    for (int it = 0; it < S / 64; ++it) {
        if (it + 2 < S / 64) {
            int nb = cur + 2; if (nb >= 3) nb -= 3;
            STAGE(it + 2, nb)    // overwrites buf[(it-1)%3] — sealed
        }
        // gate: tile it's DMAs done (FIFO in-order); deeper tiles in flight
        if (it == 0)
            asm volatile("s_waitcnt vmcnt(8) lgkmcnt(0)" ::: "memory");
        else if (it + 2 < S / 64)
            asm volatile("s_waitcnt vmcnt(8)" ::: "memory");
        else if (it + 2 == S / 64)
            asm volatile("s_waitcnt vmcnt(4)" ::: "memory");
        else
            asm volatile("s_waitcnt vmcnt(0)" ::: "memory");
        BARRIER();   // tile it visible to all waves

        __builtin_amdgcn_s_setprio(1);
#pragma unroll
        for (int t = 0; t < 4; ++t) {
            // swapped QK^T: S[key = t*16+4lg+j][q = lc]; C-init = mask bias
            const int krow = (t * 16 + lc) * 64;
            const f16x8 kfa =
                *(const f16x8*)&ksm[cur][krow + (lg ^ (lc & 7)) * 8];
            const f16x8 kfb =
                *(const f16x8*)&ksm[cur][krow + ((4 + lg) ^ (lc & 7)) * 8];
            const f32x4 mb = *(const f32x4*)&mbias[it * 64 + t * 16 + 4 * lg];

            f16x4 pp[4];
#pragma unroll
            for (int qg = 0; qg < 4; ++qg) {
                f32x4 c = mb;
                c = __builtin_amdgcn_mfma_f32_16x16x32_f16(kfa, qf[qg][0], c, 0, 0, 0);
                c = __builtin_amdgcn_mfma_f32_16x16x32_f16(kfb, qf[qg][1], c, 0, 0, 0);
                const auto u0 = __builtin_amdgcn_cvt_pkrtz(EXP2(c[0]), EXP2(c[1]));
                const auto u1 = __builtin_amdgcn_cvt_pkrtz(EXP2(c[2]), EXP2(c[3]));
                lsum[qg] = __builtin_amdgcn_fdot2(u0, ones, lsum[qg], false);
                lsum[qg] = __builtin_amdgcn_fdot2(u1, ones, lsum[qg], false);
                pp[qg][0] = (_Float16)u0[0]; pp[qg][1] = (_Float16)u0[1];
                pp[qg][2] = (_Float16)u1[0]; pp[qg][3] = (_Float16)u1[1];
            }

            // PV over this 16-key tile: 4 hd-groups; V frags shared by 4 qg
#pragma unroll
            for (int g = 0; g < 4; ++g) {
                const int vrow = (g * 16 + lc) * 64;
                const f16x4 vf = *(const f16x4*)&vsm[cur][
                    vrow + (((2 * t + (lg >> 1)) ^ (lc & 7)) << 3) + (lg & 1) * 4];
#pragma unroll
                for (int qg = 0; qg < 4; ++qg)
                    acc[qg][g] = __builtin_amdgcn_mfma_f32_16x16x16f16(
                        pp[qg], vf, acc[qg][g], 0, 0, 0);
            }
        }
        __builtin_amdgcn_s_setprio(0);
        BARRIER();   // all waves done reading buf[cur]
        if (++cur >= 3) cur = 0;
    }
#undef STAGE

    // epilogue: reduce l across lg-groups, redistribute, normalize, write
#pragma unroll
    for (int qg = 0; qg < 4; ++qg) {
        float l = lsum[qg];
        l += __shfl_xor(l, 16);
        l += __shfl_xor(l, 32);
        const float inv = l > 0.f ? 1.f / l : 0.f;
#pragma unroll
        for (int j = 0; j < 4; ++j) {
            const int qin = 4 * lg + j;
            const float ij = __shfl(inv, qin);
            const int qr = qt * 256 + qg * 64 + w * 16 + qin;
            const float iq = mrow[qr] ? ij : 0.f;
            const size_t o = ((size_t)(b * S + qr)) * D + h * HD;
#pragma unroll
            for (int g = 0; g < 4; ++g)
                ctx[o + 16 * g + lc] = (_Float16)(acc[qg][g][j] * iq);
        }
    }
}

// -------------------------------------------------------------------------------
extern "C" void kernel_launch(void* const* d_in, const int* in_sizes, int n_in,
                              void* d_out, int out_size, void* d_ws, size_t ws_size,
                              hipStream_t stream) {
    const float* hidden = (const float*)d_in[0];
    const unsigned char* maskraw = (const unsigned char*)d_in[1];
    const float* qkv_w = (const float*)d_in[2];
    const float* qkv_b = (const float*)d_in[3];
    const float* proj_w = (const float*)d_in[4];
    const float* proj_b = (const float*)d_in[5];
    float* out = (float*)d_out;

    char* ws = (char*)d_ws;
    size_t off = 0;
    int* maskN = (int*)(ws + off);            off += (size_t)NTOK * 4;
    _Float16* hid16 = (_Float16*)(ws + off);  off += (size_t)NTOK * D * 2;
    _Float16* qkvw16 = (_Float16*)(ws + off); off += (size_t)QKV_N * D * 2;
    _Float16* projw16 = (_Float16*)(ws + off); off += (size_t)D * D * 2;
    _Float16* qkv16 = (_Float16*)(ws + off);  off += (size_t)NTOK * QKV_N * 2;
    _Float16* vt = (_Float16*)(ws + off);     off += (size_t)NTOK * D * 2;
    _Float16* ctx16 = (_Float16*)(ws + off);  off += (size_t)NTOK * D * 2;

    normalize_mask_kernel<<<1, 256, 0, stream>>>(maskraw, maskN, NTOK);

    const int n0 = NTOK * D / 4, n1 = QKV_N * D / 4, n2 = D * D / 4;
    cvt_all_f16<<<(n0 + n1 + n2 + 255) / 256, 256, 0, stream>>>(
        hidden, hid16, n0, qkv_w, qkvw16, n1, proj_w, projw16, n2);

    // qkv GEMM (+fused V-transpose): 128*18 = 2304 blocks
    gemm16<1><<<dim3(2304), 256, 0, stream>>>(
        hid16, qkvw16, qkv_b, nullptr, QKV_N, nullptr, qkv16, vt);

    attn_kernel<<<dim3(B * H * (S / 256)), 256, 0, stream>>>(qkv16, vt, maskN, ctx16);

    // proj GEMM: 128*6 = 768 blocks
    gemm16<0><<<dim3(768), 256, 0, stream>>>(
        ctx16, projw16, proj_b, maskN, D, out, nullptr, nullptr);
}

// Round 17
// 191.116 us; speedup vs baseline: 1.3284x; 1.0469x over previous
//
#include <hip/hip_runtime.h>
#include <cstdint>
#include <cstddef>

#define B 16
#define S 1024
#define D 768
#define H 12
#define HD 64
#define NTOK (B * S)        // 16384
#define QKV_N (3 * D)       // 2304
#define SCALE 0.125f        // 64^-0.5
#define C2 2.88539008f      // 2.0 * log2(e): fixed softmax shift (nat-log C=2)
#define GK 768              // GEMM contraction dim (both GEMMs)
#define NT_K 12             // GK / 64

typedef _Float16 f16x8 __attribute__((ext_vector_type(8)));
typedef _Float16 f16x4 __attribute__((ext_vector_type(4)));
typedef __fp16 fp16x2 __attribute__((ext_vector_type(2)));
typedef float f32x4 __attribute__((ext_vector_type(4)));

typedef __attribute__((address_space(3))) void as3_void;
typedef const __attribute__((address_space(1))) void as1_void;

#if defined(__has_builtin)
#if __has_builtin(__builtin_amdgcn_exp2f)
#define EXP2(x) __builtin_amdgcn_exp2f(x)
#else
#define EXP2(x) exp2f(x)
#endif
#else
#define EXP2(x) exp2f(x)
#endif

// s_barrier WITH compiler memory fence.
#define BARRIER() asm volatile("s_barrier" ::: "memory")

// ---------------- mask normalization (bool-byte vs int32 agnostic) -------------
__global__ __launch_bounds__(256) void normalize_mask_kernel(
    const unsigned char* __restrict__ raw, int* __restrict__ outm, int n) {
    __shared__ int s_isbyte;
    const int tid = threadIdx.x;
    if (tid == 0) s_isbyte = 0;
    __syncthreads();
    int found = 0;
    for (int i = tid; i < n; i += 256) {
        if ((i & 3) != 0 && raw[i] != 0) found = 1;
    }
    if (found) atomicOr(&s_isbyte, 1);
    __syncthreads();
    const int isbyte = s_isbyte;
    if (isbyte) {
        for (int i = tid; i < n; i += 256) outm[i] = raw[i] ? 1 : 0;
    } else {
        const int* r32 = (const int*)raw;
        for (int i = tid; i < n; i += 256) outm[i] = r32[i] ? 1 : 0;
    }
}

// ---------------- f32 -> f16 conversion (3 tensors, one launch) ----------------
__global__ __launch_bounds__(256) void cvt_all_f16(
    const float* __restrict__ in0, _Float16* __restrict__ out0, int n0,
    const float* __restrict__ in1, _Float16* __restrict__ out1, int n1,
    const float* __restrict__ in2, _Float16* __restrict__ out2, int n2) {
    int i = blockIdx.x * 256 + threadIdx.x;
    const float* in;
    _Float16* out;
    if (i < n0) { in = in0; out = out0; }
    else if (i < n0 + n1) { i -= n0; in = in1; out = out1; }
    else { i -= n0 + n1; in = in2; out = out2; if (i >= n2) return; }
    const float4 v = ((const float4*)in)[i];
    f16x4 o;
    o[0] = (_Float16)v.x; o[1] = (_Float16)v.y;
    o[2] = (_Float16)v.z; o[3] = (_Float16)v.w;
    ((f16x4*)out)[i] = o;
}

// ---------------- f16 MFMA GEMM: C[m,n] = sum_k A[m,k]*W[n,k] + bias[n] --------
// 128x128 tile, BK=64, 256 threads = 4 waves (2x2 of 64x64).
// Double-buffered LDS + counted vmcnt(8) across fenced s_barrier.
// XOR swizzle (slot ^= row&7) on global source AND ds_read addr (conflict-free).
// MODE 1 (QKV): Q,K column-blocks (bn<1536) -> row-major f16 qkv16;
//               V column-blocks (bn>=1536, never straddle) -> transposed into
//               vt[B,H,64,S] via post-loop LDS transpose (smem reuse).
// MODE 0 (proj): f32 out + rowmask zeroing.
template <int MODE>
__global__ __launch_bounds__(256, 2) void gemm16(
    const _Float16* __restrict__ A, const _Float16* __restrict__ Wm,
    const float* __restrict__ bias, const int* __restrict__ rowmask,
    int N, float* __restrict__ outf, _Float16* __restrict__ outh,
    _Float16* __restrict__ vtb) {
    __shared__ _Float16 smem[32768];   // 64 KB: As[2]=smem+buf*8192, Bs[2]=+16384

    const int tid = threadIdx.x;
    const int w = tid >> 6, l = tid & 63;
    const int wm = (w >> 1) * 64, wn = (w & 1) * 64;
    const int lg = l >> 4, lc = l & 15;

    // XCD-aware decode: bid%8 = XCD; per XCD a 16-row M-stripe, N-major inside.
    const int bid = blockIdx.x;
    const int xcd = bid & 7;
    const int idx = bid >> 3;
    const int bn = (idx >> 4) * 128;
    const int bm = (xcd * 16 + (idx & 15)) * 128;

    f32x4 acc[4][4] = {};

#define STAGE(T, BUF)                                                           \
    {                                                                           \
        const int kt_ = (T) * 64;                                               \
        _Pragma("unroll")                                                       \
        for (int i_ = 0; i_ < 4; ++i_) {                                        \
            const int ci_ = (w << 2) + i_;       /* 0..15 */                    \
            const int r_ = (ci_ << 3) + (l >> 3);                               \
            const int c16_ = (l & 7) ^ (r_ & 7);                                \
            __builtin_amdgcn_global_load_lds(                                   \
                (as1_void*)(A + (size_t)(bm + r_) * GK + kt_ + c16_ * 8),       \
                (as3_void*)(smem + (BUF) * 8192 + ci_ * 512), 16, 0, 0);        \
            __builtin_amdgcn_global_load_lds(                                   \
                (as1_void*)(Wm + (size_t)(bn + r_) * GK + kt_ + c16_ * 8),      \
                (as3_void*)(smem + 16384 + (BUF) * 8192 + ci_ * 512), 16, 0, 0);\
        }                                                                       \
    }

    STAGE(0, 0)

    for (int t = 0; t < NT_K; ++t) {
        const int cur = t & 1;
        if (t + 1 < NT_K) {
            STAGE(t + 1, cur ^ 1)
            asm volatile("s_waitcnt vmcnt(8)" ::: "memory");
        } else {
            asm volatile("s_waitcnt vmcnt(0)" ::: "memory");
        }
        BARRIER();   // buf[cur] populated & visible

        const _Float16* sA = smem + cur * 8192;
        const _Float16* sB = smem + 16384 + cur * 8192;
        __builtin_amdgcn_s_setprio(1);
#pragma unroll
        for (int kk = 0; kk < 2; ++kk) {
            const int c16 = ((kk << 2) + lg) ^ (lc & 7);
            f16x8 af[4], bf[4];
#pragma unroll
            for (int ni = 0; ni < 4; ++ni)
                bf[ni] = *(const f16x8*)&sB[(wn + ni * 16 + lc) * 64 + c16 * 8];
#pragma unroll
            for (int mi = 0; mi < 4; ++mi)
                af[mi] = *(const f16x8*)&sA[(wm + mi * 16 + lc) * 64 + c16 * 8];
#pragma unroll
            for (int mi = 0; mi < 4; ++mi)
#pragma unroll
                for (int ni = 0; ni < 4; ++ni)
                    acc[mi][ni] = __builtin_amdgcn_mfma_f32_16x16x32_f16(
                        af[mi], bf[ni], acc[mi][ni], 0, 0, 0);
        }
        __builtin_amdgcn_s_setprio(0);
        BARRIER();   // all waves done reading buf[cur]
    }
#undef STAGE

    float bs[4];
#pragma unroll
    for (int ni = 0; ni < 4; ++ni) bs[ni] = bias[bn + wn + ni * 16 + lc];

    if (MODE == 1) {
        if (bn < 1536) {
            // Q,K: row-major f16
#pragma unroll
            for (int mi = 0; mi < 4; ++mi) {
#pragma unroll
                for (int j = 0; j < 4; ++j) {
                    const int m = bm + wm + mi * 16 + lg * 4 + j;
#pragma unroll
                    for (int ni = 0; ni < 4; ++ni) {
                        const int col = bn + wn + ni * 16 + lc;
                        outh[(size_t)m * N + col] =
                            (_Float16)(acc[mi][ni][j] + bs[ni]);
                    }
                }
            }
        } else {
            // V: transpose via LDS (smem reuse; [128 col][136] stride)
#pragma unroll
            for (int mi = 0; mi < 4; ++mi) {
#pragma unroll
                for (int ni = 0; ni < 4; ++ni) {
                    f16x4 v4;
#pragma unroll
                    for (int j = 0; j < 4; ++j)
                        v4[j] = (_Float16)(acc[mi][ni][j] + bs[ni]);
                    const int nl = wn + ni * 16 + lc;
                    const int ml = wm + mi * 16 + lg * 4;
                    *(f16x4*)&smem[nl * 136 + ml] = v4;
                }
            }
            __syncthreads();
            const int r = tid >> 1;            // local col 0..127 (hd dim)
            const int c0 = (tid & 1) * 64;     // token sub-block
            const int col0 = bn - 1536 + r;    // 0..767
            const int hh = col0 >> 6, hd = col0 & 63;
            const int bb = bm >> 10;
            const int s0 = (bm & 1023) + c0;
            _Float16* dst = vtb + ((size_t)(bb * H + hh) * HD + hd) * S + s0;
#pragma unroll
            for (int e = 0; e < 8; ++e)
                *(f16x8*)(dst + e * 8) = *(const f16x8*)&smem[r * 136 + c0 + e * 8];
        }
    } else {
#pragma unroll
        for (int mi = 0; mi < 4; ++mi) {
#pragma unroll
            for (int j = 0; j < 4; ++j) {
                const int m = bm + wm + mi * 16 + lg * 4 + j;
                const int mv = rowmask[m];
#pragma unroll
                for (int ni = 0; ni < 4; ++ni) {
                    const int col = bn + wn + ni * 16 + lc;
                    outf[(size_t)m * N + col] = mv ? acc[mi][ni][j] + bs[ni] : 0.f;
                }
            }
        }
    }
}

// ---------------- flash attention: swapped QK^T, register-resident P ----------
// grid: B*H*(S/256) = 768 = 3 blocks/CU exactly, XCD-grouped. QBLK=256.
// THREE K/V LDS buffers, depth-2 DMA pipeline, counted vmcnt, fenced barriers.
// PV now uses 16x16x32 MFMA over 32-key pairs (k-slot permutation shared by
// P-pack and V-frag): half the PV MFMA instructions vs 16x16x16 (r16's
// matrix-pipe floor analysis: PV at K=16 wastes half the pipe).
__global__ __launch_bounds__(256, 3) void attn_kernel(
    const _Float16* __restrict__ qkv, const _Float16* __restrict__ vtb,
    const int* __restrict__ mask, _Float16* __restrict__ ctx) {
    __shared__ _Float16 ksm[3][64 * 64];   // 24 KB
    __shared__ _Float16 vsm[3][64 * 64];   // 24 KB
    __shared__ float mbias[S];             // 4 KB

    const int blk = blockIdx.x;
    // XCD grouping: 768 blocks = 8 xcd * 24 bh * 4 qt
    const int xcd = blk & 7;
    const int idx = blk >> 3;
    const int bh_ = xcd * 24 + (idx >> 2);
    const int qt = idx & 3;
    const int h = bh_ % H;
    const int b = bh_ / H;
    const int tid = threadIdx.x;
    const int w = tid >> 6, lane = tid & 63;
    const int lg = lane >> 4, lc = lane & 15;

    const size_t bh = (size_t)(b * H + h);
    const _Float16* Kp = qkv + (size_t)(b * S) * QKV_N + D + h * HD; // +row*2304
    const _Float16* Vt = vtb + bh * HD * S;
    const int* mrow = mask + b * S;

    // DMA staging geometry: instr covers rows r0 (and r0+32); LDS linear dest,
    // global source col16 XOR-swizzled by row. (32+r0)&7 == r0&7.
    const int r0 = w * 8 + (lane >> 3);
    const int swz8 = ((lane & 7) ^ (r0 & 7)) * 8;
    const int koff0 = r0 * QKV_N + swz8;
    const int koff1 = (32 + r0) * QKV_N + swz8;
    const int voff0 = r0 * S + swz8;
    const int voff1 = (32 + r0) * S + swz8;

// T = tile index (keys T*64 .. T*64+63)
#define STAGE(T, BUF)                                                          \
    {                                                                          \
        const int kt_ = (T) * 64;                                              \
        __builtin_amdgcn_global_load_lds(                                      \
            (as1_void*)(Kp + (size_t)kt_ * QKV_N + koff0),                     \
            (as3_void*)(&ksm[BUF][w * 512]), 16, 0, 0);                        \
        __builtin_amdgcn_global_load_lds(                                      \
            (as1_void*)(Kp + (size_t)kt_ * QKV_N + koff1),                     \
            (as3_void*)(&ksm[BUF][2048 + w * 512]), 16, 0, 0);                 \
        __builtin_amdgcn_global_load_lds(                                      \
            (as1_void*)(Vt + (size_t)kt_ + voff0),                            \
            (as3_void*)(&vsm[BUF][w * 512]), 16, 0, 0);                        \
        __builtin_amdgcn_global_load_lds(                                      \
            (as1_void*)(Vt + (size_t)kt_ + voff1),                            \
            (as3_void*)(&vsm[BUF][2048 + w * 512]), 16, 0, 0);                 \
    }

    // Q fragments: four q-groups (rows +0,+64,+128,+192), pre-scaled
    const int qbase = qt * 256 + w * 16 + lc;
    const _Float16 qs = (_Float16)(0.125f * 1.44269504f);
    f16x8 qf[4][2];
#pragma unroll
    for (int qg = 0; qg < 4; ++qg) {
        const _Float16* Qp =
            qkv + (size_t)(b * S + qbase + qg * 64) * QKV_N + h * HD;
        qf[qg][0] = *(const f16x8*)(Qp + lg * 8);
        qf[qg][1] = *(const f16x8*)(Qp + 32 + lg * 8);
        qf[qg][0] *= qs;
        qf[qg][1] *= qs;
    }

    // mask-bias table (all 1024 keys, once): valid ? -C2 : -1e9
#pragma unroll
    for (int i = 0; i < 4; ++i)
        mbias[i * 256 + tid] = mrow[i * 256 + tid] ? -C2 : -1e9f;

    // prologue: depth-2 fill (tiles 0 and 1)
    STAGE(0, 0)
    STAGE(1, 1)

    f32x4 acc[4][4] = {};
    float lsum[4] = {0.f, 0.f, 0.f, 0.f};
    fp16x2 ones;
    ones[0] = (__fp16)1.0f; ones[1] = (__fp16)1.0f;

    int cur = 0;
    for (int it = 0; it < S / 64; ++it) {
        if (it + 2 < S / 64) {
            int nb = cur + 2; if (nb >= 3) nb -= 3;
            STAGE(it + 2, nb)    // overwrites buf[(it-1)%3] — sealed
        }
        // gate: tile it's DMAs done (FIFO in-order); deeper tiles in flight
        if (it == 0)
            asm volatile("s_waitcnt vmcnt(8) lgkmcnt(0)" ::: "memory");
        else if (it + 2 < S / 64)
            asm volatile("s_waitcnt vmcnt(8)" ::: "memory");
        else if (it + 2 == S / 64)
            asm volatile("s_waitcnt vmcnt(4)" ::: "memory");
        else
            asm volatile("s_waitcnt vmcnt(0)" ::: "memory");
        BARRIER();   // tile it visible to all waves

        __builtin_amdgcn_s_setprio(1);
#pragma unroll
        for (int u = 0; u < 2; ++u) {    // pair of 16-key subtiles (32 keys)
            f16x8 pp8[4];
#pragma unroll
            for (int s = 0; s < 2; ++s) {
                const int t = 2 * u + s;
                // swapped QK^T: S[key = t*16+4lg+j][q = lc]; C-init = mask bias
                const int krow = (t * 16 + lc) * 64;
                const f16x8 kfa =
                    *(const f16x8*)&ksm[cur][krow + (lg ^ (lc & 7)) * 8];
                const f16x8 kfb =
                    *(const f16x8*)&ksm[cur][krow + ((4 + lg) ^ (lc & 7)) * 8];
                const f32x4 mb = *(const f32x4*)&mbias[it * 64 + t * 16 + 4 * lg];
#pragma unroll
                for (int qg = 0; qg < 4; ++qg) {
                    f32x4 c = mb;
                    c = __builtin_amdgcn_mfma_f32_16x16x32_f16(kfa, qf[qg][0], c, 0, 0, 0);
                    c = __builtin_amdgcn_mfma_f32_16x16x32_f16(kfb, qf[qg][1], c, 0, 0, 0);
                    const auto u0 = __builtin_amdgcn_cvt_pkrtz(EXP2(c[0]), EXP2(c[1]));
                    const auto u1 = __builtin_amdgcn_cvt_pkrtz(EXP2(c[2]), EXP2(c[3]));
                    lsum[qg] = __builtin_amdgcn_fdot2(u0, ones, lsum[qg], false);
                    lsum[qg] = __builtin_amdgcn_fdot2(u1, ones, lsum[qg], false);
                    pp8[qg][s * 4 + 0] = (_Float16)u0[0];
                    pp8[qg][s * 4 + 1] = (_Float16)u0[1];
                    pp8[qg][s * 4 + 2] = (_Float16)u1[0];
                    pp8[qg][s * 4 + 3] = (_Float16)u1[1];
                }
            }

            // PV over 32 keys via 16x16x32: k-slot (lg,e) <-> key
            // sigma = 32u + (e<4?0:16) + 4lg + (e&3); A(pp8) and B(vf8) agree.
#pragma unroll
            for (int g = 0; g < 4; ++g) {
                const int vrow = (g * 16 + lc) * 64;
                const int cA = ((4 * u + (lg >> 1)) ^ (lc & 7)) * 8 + (lg & 1) * 4;
                const int cB = ((4 * u + 2 + (lg >> 1)) ^ (lc & 7)) * 8 + (lg & 1) * 4;
                const f16x4 vlo = *(const f16x4*)&vsm[cur][vrow + cA];
                const f16x4 vhi = *(const f16x4*)&vsm[cur][vrow + cB];
                f16x8 vf8;
                vf8[0] = vlo[0]; vf8[1] = vlo[1]; vf8[2] = vlo[2]; vf8[3] = vlo[3];
                vf8[4] = vhi[0]; vf8[5] = vhi[1]; vf8[6] = vhi[2]; vf8[7] = vhi[3];
#pragma unroll
                for (int qg = 0; qg < 4; ++qg)
                    acc[qg][g] = __builtin_amdgcn_mfma_f32_16x16x32_f16(
                        pp8[qg], vf8, acc[qg][g], 0, 0, 0);
            }
        }
        __builtin_amdgcn_s_setprio(0);
        BARRIER();   // all waves done reading buf[cur]
        if (++cur >= 3) cur = 0;
    }
#undef STAGE

    // epilogue: reduce l across lg-groups, redistribute, normalize, write
#pragma unroll
    for (int qg = 0; qg < 4; ++qg) {
        float l = lsum[qg];
        l += __shfl_xor(l, 16);
        l += __shfl_xor(l, 32);
        const float inv = l > 0.f ? 1.f / l : 0.f;
#pragma unroll
        for (int j = 0; j < 4; ++j) {
            const int qin = 4 * lg + j;
            const float ij = __shfl(inv, qin);
            const int qr = qt * 256 + qg * 64 + w * 16 + qin;
            const float iq = mrow[qr] ? ij : 0.f;
            const size_t o = ((size_t)(b * S + qr)) * D + h * HD;
#pragma unroll
            for (int g = 0; g < 4; ++g)
                ctx[o + 16 * g + lc] = (_Float16)(acc[qg][g][j] * iq);
        }
    }
}

// -------------------------------------------------------------------------------
extern "C" void kernel_launch(void* const* d_in, const int* in_sizes, int n_in,
                              void* d_out, int out_size, void* d_ws, size_t ws_size,
                              hipStream_t stream) {
    const float* hidden = (const float*)d_in[0];
    const unsigned char* maskraw = (const unsigned char*)d_in[1];
    const float* qkv_w = (const float*)d_in[2];
    const float* qkv_b = (const float*)d_in[3];
    const float* proj_w = (const float*)d_in[4];
    const float* proj_b = (const float*)d_in[5];
    float* out = (float*)d_out;

    char* ws = (char*)d_ws;
    size_t off = 0;
    int* maskN = (int*)(ws + off);            off += (size_t)NTOK * 4;
    _Float16* hid16 = (_Float16*)(ws + off);  off += (size_t)NTOK * D * 2;
    _Float16* qkvw16 = (_Float16*)(ws + off); off += (size_t)QKV_N * D * 2;
    _Float16* projw16 = (_Float16*)(ws + off); off += (size_t)D * D * 2;
    _Float16* qkv16 = (_Float16*)(ws + off);  off += (size_t)NTOK * QKV_N * 2;
    _Float16* vt = (_Float16*)(ws + off);     off += (size_t)NTOK * D * 2;
    _Float16* ctx16 = (_Float16*)(ws + off);  off += (size_t)NTOK * D * 2;

    normalize_mask_kernel<<<1, 256, 0, stream>>>(maskraw, maskN, NTOK);

    const int n0 = NTOK * D / 4, n1 = QKV_N * D / 4, n2 = D * D / 4;
    cvt_all_f16<<<(n0 + n1 + n2 + 255) / 256, 256, 0, stream>>>(
        hidden, hid16, n0, qkv_w, qkvw16, n1, proj_w, projw16, n2);

    // qkv GEMM (+fused V-transpose): 128*18 = 2304 blocks
    gemm16<1><<<dim3(2304), 256, 0, stream>>>(
        hid16, qkvw16, qkv_b, nullptr, QKV_N, nullptr, qkv16, vt);

    attn_kernel<<<dim3(B * H * (S / 256)), 256, 0, stream>>>(qkv16, vt, maskN, ctx16);

    // proj GEMM: 128*6 = 768 blocks
    gemm16<0><<<dim3(768), 256, 0, stream>>>(
        ctx16, projw16, proj_b, maskN, D, out, nullptr, nullptr);
}